// Round 15
// baseline (520.588 us; speedup 1.0000x reference)
//
#include <hip/hip_runtime.h>
#include <hip/hip_bf16.h>
#include <math.h>

#define Bb 2
#define Tt 2048
#define Cc 2048
#define Hh 16
#define CONVD 6144
#define Mrows 4096  // B*T
#define NCHUNK 32   // T / 64

typedef __attribute__((ext_vector_type(8))) short short8v;
typedef __attribute__((ext_vector_type(4))) float floatx4;

__device__ __forceinline__ unsigned short f2bf(float f) {
    __hip_bfloat16 h = __float2bfloat16(f);
    return __builtin_bit_cast(unsigned short, h);
}

__device__ __forceinline__ void load_lds16(const void* g, void* l) {
    __builtin_amdgcn_global_load_lds(
        (const __attribute__((address_space(1))) void*)g,
        (__attribute__((address_space(3))) void*)l, 16, 0, 0);
}

// col-swizzle for float LDS tiles with 128-col rows read as float4 at tj*8:
__device__ __forceinline__ int swz8(int col) {
    return col ^ (((col >> 5) & 3) << 3);
}

#define LGKM0 asm volatile("s_waitcnt lgkmcnt(0)" ::: "memory")
#define VMC8  asm volatile("s_waitcnt vmcnt(8)" ::: "memory")
#define VMC4  asm volatile("s_waitcnt vmcnt(4)" ::: "memory")
#define VMC0  asm volatile("s_waitcnt vmcnt(0)" ::: "memory")
#define SCHB  __builtin_amdgcn_sched_barrier(0)
#define SBAR  __builtin_amdgcn_s_barrier()

// ------ merged transpose+cast: W1(2048x8192)->WT1, W2(2048x2048)->WT2 -------
__global__ __launch_bounds__(256) void transpose_cast2(
    const float* __restrict__ W1, unsigned short* __restrict__ WT1,
    const float* __restrict__ W2, unsigned short* __restrict__ WT2)
{
    const float* W; unsigned short* WT; int Nn;
    if (blockIdx.z == 0) { W = W1; WT = WT1; Nn = 8192; }
    else                 { W = W2; WT = WT2; Nn = 2048; if (blockIdx.x >= 64) return; }
    __shared__ float tile[32][33];
    const int n0 = blockIdx.x * 32;
    const int k0 = blockIdx.y * 32;
    const int tx = threadIdx.x & 31;
    const int ty = threadIdx.x >> 5;
#pragma unroll
    for (int r = ty; r < 32; r += 8)
        tile[r][tx] = W[(size_t)(k0 + r) * Nn + n0 + tx];
    __syncthreads();
#pragma unroll
    for (int r = ty; r < 32; r += 8)
        WT[(size_t)(n0 + r) * 2048 + k0 + tx] = f2bf(tile[tx][r]);
}

// ====== 256x256 bf16 MFMA GEMM: 4-deep counted-vmcnt + 2-phase barriers =====
// r10 wait structure (4 bufs, stage t+3, vmcnt(8) per tile) + m201 phase body:
// per tile 2 phases, each {ds_reads + half-stage -> SBAR -> lgkmcnt(0) ->
// setprio(1) 16 MFMA setprio(0) -> SBAR}. The inter-phase barriers force the
// wave-lockstep phase rotation m201 needs (r13 lacked them -> neutral); the
// counted vmcnt avoids r8/r9's drain stall.
__global__ __launch_bounds__(512) void gemm256(
    const unsigned short* __restrict__ A, const unsigned short* __restrict__ Bt,
    float* __restrict__ C1, float* __restrict__ C2,
    int Kk, int lda, int ldb)
{
    __shared__ __align__(16) unsigned short A_lds[4][256 * 32];
    __shared__ __align__(16) unsigned short B_lds[4][256 * 32];

    const int tid  = threadIdx.x;
    const int wid  = tid >> 6;            // 0..7
    const int lane = tid & 63;
    const int wr = wid >> 2, wc = wid & 3;
    const int l15 = lane & 15, kq = lane >> 4;

    const int rr = lane >> 2;
    const int cs = (lane & 3) ^ ((rr >> 1) & 3);
    const int fch = (kq ^ ((l15 >> 1) & 3)) << 3;   // in shorts

    // 8x8 super-chunk per XCD (grid 32x16, 512 blocks, bijective)
    const int bid = blockIdx.y * 32 + blockIdx.x;
    const int xcd = bid & 7;
    const int idx = bid >> 3;
    const int block_m = ((xcd >> 2) * 8 + (idx >> 3)) * 256;
    const int block_n = ((xcd & 3) * 8 + (idx & 7)) * 256;

    const unsigned short* Ag = A + (size_t)block_m * lda;
    const unsigned short* Bg = Bt + (size_t)block_n * ldb;

    const int NT = Kk >> 5;               // K-tiles of 32

#define STGH(bi, kk0, j_) do {                                               \
    unsigned short* la_ = &A_lds[(bi)][0];                                   \
    unsigned short* lb_ = &B_lds[(bi)][0];                                   \
    const int brow = wid * 32 + (j_) * 16;                                   \
    load_lds16(Ag + (size_t)(brow + rr) * lda + (kk0) + cs * 8,              \
               la_ + brow * 32);                                             \
    load_lds16(Bg + (size_t)(brow + rr) * ldb + (kk0) + cs * 8,              \
               lb_ + brow * 32);                                             \
} while (0)

    floatx4 acc[8][4] = {};

    // prologue: stage tiles 0,1,2 (12 loads/wave), wait tile0, sync
    STGH(0, 0, 0);  STGH(0, 0, 1);
    STGH(1, 32, 0); STGH(1, 32, 1);
    STGH(2, 64, 0); STGH(2, 64, 1);
    VMC8; SCHB; SBAR;

    for (int t = 0; t < NT; ++t) {
        const unsigned short* la = &A_lds[t & 3][0];
        const unsigned short* lb = &B_lds[t & 3][0];
        const bool pf = (t + 3 < NT);
        const int pbi = (t + 3) & 3, pk0 = (t + 3) << 5;

        short8v af[8], bf[4];
        // -------- phase 0: af0-3 + bf0-3 (8 reads), half stage, 16 MFMA ----
#pragma unroll
        for (int mf = 0; mf < 4; ++mf)
            af[mf] = *(const short8v*)(la + (wr * 128 + mf * 16 + l15) * 32 + fch);
#pragma unroll
        for (int nf = 0; nf < 4; ++nf)
            bf[nf] = *(const short8v*)(lb + (wc * 64 + nf * 16 + l15) * 32 + fch);
        if (pf) STGH(pbi, pk0, 0);
        SCHB; SBAR;
        LGKM0; SCHB;
        __builtin_amdgcn_s_setprio(1);
#pragma unroll
        for (int mf = 0; mf < 4; ++mf)
#pragma unroll
            for (int nf = 0; nf < 4; ++nf)
                acc[mf][nf] = __builtin_amdgcn_mfma_f32_16x16x32_bf16(
                    af[mf], bf[nf], acc[mf][nf], 0, 0, 0);
        __builtin_amdgcn_s_setprio(0);
        SCHB; SBAR;
        // -------- phase 1: af4-7 (4 reads), other half stage, 16 MFMA ------
#pragma unroll
        for (int mf = 4; mf < 8; ++mf)
            af[mf] = *(const short8v*)(la + (wr * 128 + mf * 16 + l15) * 32 + fch);
        if (pf) STGH(pbi, pk0, 1);
        SCHB; SBAR;
        LGKM0; SCHB;
        __builtin_amdgcn_s_setprio(1);
#pragma unroll
        for (int mf = 4; mf < 8; ++mf)
#pragma unroll
            for (int nf = 0; nf < 4; ++nf)
                acc[mf][nf] = __builtin_amdgcn_mfma_f32_16x16x32_bf16(
                    af[mf], bf[nf], acc[mf][nf], 0, 0, 0);
        __builtin_amdgcn_s_setprio(0);
        SCHB;
        // -------- tile end: counted wait (never a drain mid-loop) ----------
        if (t + 1 < NT) {
            if      (t + 3 < NT) { VMC8; }   // t+1 landed; t+2,t+3 in flight
            else if (t + 2 < NT) { VMC4; }
            else                 { VMC0; }
            SCHB;
        }
        SBAR;
    }
#undef STGH

    // C-write, split per block column (uniform per block)
    float* Cp; int col0; size_t ldc;
    if (block_n < 6144) { Cp = C1; col0 = block_n;        ldc = 6144; }
    else                { Cp = C2; col0 = block_n - 6144; ldc = 2048; }
#pragma unroll
    for (int mf = 0; mf < 8; ++mf)
#pragma unroll
        for (int nf = 0; nf < 4; ++nf)
#pragma unroll
            for (int r = 0; r < 4; ++r) {
                int row = block_m + wr * 128 + mf * 16 + kq * 4 + r;
                int col = col0 + wc * 64 + nf * 16 + l15;
                Cp[(size_t)row * ldc + col] = acc[mf][nf][r];
            }
}

// ---- 128x128 bf16 MFMA GEMM, 4-deep counted-vmcnt pipeline (r10 pattern) ---
__global__ __launch_bounds__(256) void gemm_bf16(
    const unsigned short* __restrict__ A, const unsigned short* __restrict__ Bt,
    float* __restrict__ C, int Kk, int lda, int ldb, int ldc)
{
    __shared__ __align__(16) unsigned short A_lds[4][128 * 32];
    __shared__ __align__(16) unsigned short B_lds[4][128 * 32];

    const int tid = threadIdx.x;
    const int wid = tid >> 6;             // 0..3
    const int lane = tid & 63;
    const int wr = wid >> 1, wc = wid & 1;
    const int l15 = lane & 15, kq = lane >> 4;

    const int rr = lane >> 2;
    const int cs = (lane & 3) ^ ((rr >> 1) & 3);
    const int fch = (kq ^ ((l15 >> 1) & 3)) << 3;

    // m204 bijective XCD chunking (nwg % 8 == 0)
    const int nwg = gridDim.x * gridDim.y;
    const int bid = blockIdx.y * gridDim.x + blockIdx.x;
    const int wgid = (bid & 7) * (nwg >> 3) + (bid >> 3);
    const int block_m = (wgid / gridDim.x) * 128;
    const int block_n = (wgid % gridDim.x) * 128;

    const unsigned short* Ag = A + (size_t)block_m * lda;
    const unsigned short* Bg = Bt + (size_t)block_n * ldb;

    const int NT = Kk >> 5;

#define STG1(bi, kk0) do {                                                   \
    unsigned short* la_ = &A_lds[(bi)][0];                                   \
    unsigned short* lb_ = &B_lds[(bi)][0];                                   \
    _Pragma("unroll")                                                        \
    for (int j_ = 0; j_ < 2; ++j_) {                                         \
        const int brow = wid * 32 + j_ * 16;                                 \
        load_lds16(Ag + (size_t)(brow + rr) * lda + (kk0) + cs * 8,          \
                   la_ + brow * 32);                                         \
        load_lds16(Bg + (size_t)(brow + rr) * ldb + (kk0) + cs * 8,          \
                   lb_ + brow * 32);                                         \
    }                                                                        \
} while (0)

    floatx4 acc[4][4] = {};

    STG1(0, 0);
    STG1(1, 32);
    STG1(2, 64);
    VMC8; SCHB; SBAR;

    for (int t = 0; t < NT; ++t) {
        const unsigned short* la = &A_lds[t & 3][0];
        const unsigned short* lb = &B_lds[t & 3][0];

        short8v af[4], bf[4];
#pragma unroll
        for (int mf = 0; mf < 4; ++mf)
            af[mf] = *(const short8v*)(la + (wr * 64 + mf * 16 + l15) * 32 + fch);
#pragma unroll
        for (int nf = 0; nf < 4; ++nf)
            bf[nf] = *(const short8v*)(lb + (wc * 64 + nf * 16 + l15) * 32 + fch);

        if (t + 3 < NT) STG1((t + 3) & 3, (t + 3) << 5);

        LGKM0; SCHB;
        __builtin_amdgcn_s_setprio(1);
#pragma unroll
        for (int mf = 0; mf < 4; ++mf)
#pragma unroll
            for (int nf = 0; nf < 4; ++nf)
                acc[mf][nf] = __builtin_amdgcn_mfma_f32_16x16x32_bf16(
                    af[mf], bf[nf], acc[mf][nf], 0, 0, 0);
        __builtin_amdgcn_s_setprio(0);
        SCHB;
        if (t + 1 < NT) {
            if      (t + 3 < NT) { VMC8; }
            else if (t + 2 < NT) { VMC4; }
            else                 { VMC0; }
            SCHB; SBAR;
        }
    }
#undef STG1

#pragma unroll
    for (int mf = 0; mf < 4; ++mf)
#pragma unroll
        for (int nf = 0; nf < 4; ++nf)
#pragma unroll
            for (int r = 0; r < 4; ++r) {
                int row = block_m + wr * 64 + mf * 16 + kq * 4 + r;
                int col = block_n + wc * 64 + nf * 16 + l15;
                C[(size_t)row * ldc + col] = acc[mf][nf][r];
            }
}

// ---- alpha/beta: sigmoid(x @ W_{a,b}) + bf16 cast of x, LDS-row-shared -----
__global__ __launch_bounds__(256) void ab_kernel(
    const float* __restrict__ x, const float* __restrict__ W_b,
    const float* __restrict__ W_a, float* __restrict__ beta,
    float* __restrict__ alpha, unsigned short* __restrict__ xb)
{
    __shared__ float xs[8][2052];
    const int row0 = blockIdx.x * 8;
    const int tid = threadIdx.x;

#pragma unroll
    for (int it = 0; it < 16; ++it) {
        const int i = tid + it * 256;
        const int r = i >> 9;
        const int c4 = (i & 511) * 4;
        float4 v = *(const float4*)(x + (size_t)(row0 + r) * 2048 + c4);
        ushort4 ob;
        ob.x = f2bf(v.x); ob.y = f2bf(v.y); ob.z = f2bf(v.z); ob.w = f2bf(v.w);
        *(ushort4*)(xb + (size_t)(row0 + r) * 2048 + c4) = ob;
        *(float4*)(&xs[r][c4]) = v;
    }
    __syncthreads();

    const int mat = tid >> 7;
    const int r   = (tid >> 4) & 7;
    const int col = tid & 15;
    const float* W = mat ? W_a : W_b;
    float acc = 0.f;
#pragma unroll 8
    for (int k = 0; k < 2048; ++k)
        acc = fmaf(xs[r][k], W[(size_t)k * 16 + col], acc);
    float s = 1.f / (1.f + expf(-acc));
    float* outp = mat ? alpha : beta;
    outp[(size_t)(row0 + r) * 16 + col] = s;
}

// ------ conv(K=4) + SiLU + split + l2norm(q,k), 16 timesteps per block ------
__global__ __launch_bounds__(128) void conv_kernel(
    const float* __restrict__ qkv, const float* __restrict__ conv_w,
    const float* __restrict__ conv_state, const int* __restrict__ input_pos,
    float* __restrict__ qn, float* __restrict__ kn, float* __restrict__ vv)
{
    const int tc = blockIdx.x;
    const int hs = blockIdx.y;
    const int b  = blockIdx.z;
    const int lane = threadIdx.x;
    const int kind = hs >> 4;
    const int h = hs & 15;
    const int c = kind * 2048 + h * 128 + lane;
    const int t0 = tc * 16;
    const float keep = (input_pos[0] == 0) ? 0.f : 1.f;

    const float4 w4 = *(const float4*)(conv_w + (size_t)c * 4);

    float win0, win1, win2;
    {
        float tmp[3];
#pragma unroll
        for (int j = 0; j < 3; ++j) {
            int tau = t0 - 3 + j;
            tmp[j] = (tau >= 0) ? qkv[(size_t)(b * Tt + tau) * CONVD + c]
                   : keep * conv_state[((size_t)b * CONVD + c) * 4 + (tau + 4)];
        }
        win0 = tmp[0]; win1 = tmp[1]; win2 = tmp[2];
    }

    float y[16];
    __shared__ float red[16][2];
#pragma unroll
    for (int i = 0; i < 16; ++i) {
        float xv = qkv[(size_t)(b * Tt + t0 + i) * CONVD + c];
        float a = fmaf(w4.x, win0, fmaf(w4.y, win1, fmaf(w4.z, win2, w4.w * xv)));
        float yy = a / (1.f + expf(-a));
        win0 = win1; win1 = win2; win2 = xv;
        if (kind == 2) {
            vv[(size_t)(b * Tt + t0 + i) * 2048 + h * 128 + lane] = yy;
        } else {
            float sq = yy * yy;
            for (int off = 32; off > 0; off >>= 1) sq += __shfl_down(sq, off);
            if ((lane & 63) == 0) red[i][lane >> 6] = sq;
            y[i] = yy;
        }
    }
    if (kind == 2) return;
    __syncthreads();
#pragma unroll
    for (int i = 0; i < 16; ++i) {
        float tot = red[i][0] + red[i][1];
        float inv = 1.f / fmaxf(sqrtf(tot), 1e-12f);
        float outv = y[i] * inv;
        const size_t oidx = (size_t)(b * Tt + t0 + i) * 2048 + h * 128 + lane;
        if (kind == 0) qn[oidx] = outv;
        else           kn[oidx] = outv;
    }
}

// ================= chunked scan, stage A: per-chunk prep =====================
__global__ __launch_bounds__(256) void chunk_prep(
    const float* __restrict__ kn, const float* __restrict__ vv,
    const float* __restrict__ alpha, const float* __restrict__ beta,
    float* __restrict__ logc_g, float* __restrict__ Mbuf)
{
    const int c = blockIdx.x, h = blockIdx.y, b = blockIdx.z;
    const int tid = threadIdx.x;
    const size_t bh = (size_t)b * Hh + h;

    __shared__ float K_lds[32][128];
    __shared__ float V_lds[32][128];
    __shared__ float logc_lds[64];
    __shared__ float b_lds[64];
    __shared__ float wk_lds[64];

    if (tid < 64) {
        const int row = b * Tt + c * 64 + tid;
        float a = alpha[(size_t)row * 16 + h];
        float la = logf(a);
#pragma unroll
        for (int d = 1; d < 64; d <<= 1) {
            float n = __shfl_up(la, d);
            if (tid >= d) la += n;
        }
        logc_lds[tid] = la;
        logc_g[bh * Tt + c * 64 + tid] = la;
        b_lds[tid] = beta[(size_t)row * 16 + h];
    }
    __syncthreads();
    if (tid < 64) {
        wk_lds[tid] = expf(logc_lds[63] - logc_lds[tid]) * b_lds[tid];
    }
    __syncthreads();

    const int ti = tid >> 4;
    const int tj = tid & 15;
    const int tj8sw = swz8(tj * 8);
    float acc[8][8];
#pragma unroll
    for (int i = 0; i < 8; ++i)
#pragma unroll
        for (int j = 0; j < 8; ++j) acc[i][j] = 0.f;

    for (int half = 0; half < 2; ++half) {
        {
            const int sl = tid >> 3;
            const int c0 = (tid & 7) * 16;
            const int grow = b * Tt + c * 64 + half * 32 + sl;
            const float4* kp = (const float4*)(kn + (size_t)grow * 2048 + h * 128 + c0);
            const float4* vp = (const float4*)(vv + (size_t)grow * 2048 + h * 128 + c0);
#pragma unroll
            for (int u = 0; u < 4; ++u) {
                const int cl = c0 + u * 4;
                *(float4*)(&K_lds[sl][cl]) = kp[u];
                *(float4*)(&V_lds[sl][swz8(cl)]) = vp[u];
            }
        }
        __syncthreads();
#pragma unroll 4
        for (int s = 0; s < 32; ++s) {
            float w = wk_lds[half * 32 + s];
            float4 k0 = *(const float4*)(&K_lds[s][ti * 8]);
            float4 k1 = *(const float4*)(&K_lds[s][ti * 8 + 4]);
            float4 v0 = *(const float4*)(&V_lds[s][tj8sw]);
            float4 v1 = *(const float4*)(&V_lds[s][tj8sw + 4]);
            float wk[8] = {w*k0.x, w*k0.y, w*k0.z, w*k0.w, w*k1.x, w*k1.y, w*k1.z, w*k1.w};
            float vf[8] = {v0.x, v0.y, v0.z, v0.w, v1.x, v1.y, v1.z, v1.w};
#pragma unroll
            for (int i = 0; i < 8; ++i)
#pragma unroll
                for (int j = 0; j < 8; ++j)
                    acc[i][j] = fmaf(wk[i], vf[j], acc[i][j]);
        }
        __syncthreads();
    }
    float* mb = Mbuf + ((bh * NCHUNK) + c) * 16384;
#pragma unroll
    for (int i = 0; i < 8; ++i) {
        float4 o0 = {acc[i][0], acc[i][1], acc[i][2], acc[i][3]};
        float4 o1 = {acc[i][4], acc[i][5], acc[i][6], acc[i][7]};
        *(float4*)(mb + (size_t)(ti * 8 + i) * 128 + tj * 8) = o0;
        *(float4*)(mb + (size_t)(ti * 8 + i) * 128 + tj * 8 + 4) = o1;
    }
}

// ================= chunked scan, stage B: state recurrence ==================
__global__ __launch_bounds__(256) void state_scan(
    float* __restrict__ Mbuf, const float* __restrict__ logc_g,
    const float* __restrict__ rec_state, const int* __restrict__ input_pos)
{
    const size_t g = (size_t)blockIdx.x * 256 + threadIdx.x;
    const int bh = (int)(g >> 14);
    const float keep = (input_pos[0] == 0) ? 0.f : 1.f;

    float S = keep * rec_state[g];
    const float* lc = logc_g + (size_t)bh * Tt;
    float* base = Mbuf + (size_t)(g & ~16383ull) * NCHUNK + (g & 16383);
#pragma unroll 4
    for (int c = 0; c < NCHUNK; ++c) {
        float Atot = expf(lc[c * 64 + 63]);
        float m = base[(size_t)c * 16384];
        base[(size_t)c * 16384] = S;
        S = fmaf(Atot, S, m);
    }
}

// ================= chunked scan, stage C: per-chunk output ==================
__global__ __launch_bounds__(256) void chunk_out(
    const float* __restrict__ qn, const float* __restrict__ kn,
    const float* __restrict__ vv, const float* __restrict__ beta,
    const float* __restrict__ logc_g, const float* __restrict__ Sstates,
    const float* __restrict__ norm_w, const float* __restrict__ zbuf,
    unsigned short* __restrict__ gated_b)
{
    const int c = blockIdx.x, h = blockIdx.y, b = blockIdx.z;
    const int tid = threadIdx.x;
    const int ti = tid >> 4;
    const int tj = tid & 15;
    const size_t bh = (size_t)b * Hh + h;
    const int row0 = b * Tt + c * 64;

    __shared__ float Q_lds[64][132];
    __shared__ float Bf[64 * 68];
    __shared__ float At[64][68];
    __shared__ float logc_s[64], b_s[64];

    {
        const int r = tid >> 2, c0 = (tid & 3) * 32;
        const float4* qp = (const float4*)(qn + (size_t)(row0 + r) * 2048 + h * 128 + c0);
#pragma unroll
        for (int u = 0; u < 8; ++u)
            *(float4*)(&Q_lds[r][c0 + u * 4]) = qp[u];
    }
    if (tid < 64) {
        logc_s[tid] = logc_g[bh * Tt + c * 64 + tid];
        b_s[tid] = beta[(size_t)(row0 + tid) * 16 + h];
    }

    float acc_a[4][4] = {};
    for (int kh = 0; kh < 2; ++kh) {
        __syncthreads();
        {
            const int s = tid >> 2, c0 = (tid & 3) * 16;
            const float* kp = kn + (size_t)(row0 + s) * 2048 + h * 128 + kh * 64 + c0;
#pragma unroll
            for (int u = 0; u < 16; ++u)
                Bf[(c0 + u) * 68 + s] = kp[u];
        }
        __syncthreads();
#pragma unroll 4
        for (int kk = 0; kk < 64; ++kk) {
            float a[4];
#pragma unroll
            for (int r = 0; r < 4; ++r) a[r] = Q_lds[ti * 4 + r][kh * 64 + kk];
            float4 bq = *(const float4*)(&Bf[kk * 68 + tj * 4]);
            float bb[4] = {bq.x, bq.y, bq.z, bq.w};
#pragma unroll
            for (int r = 0; r < 4; ++r)
#pragma unroll
                for (int cc = 0; cc < 4; ++cc)
                    acc_a[r][cc] = fmaf(a[r], bb[cc], acc_a[r][cc]);
        }
    }

#pragma unroll
    for (int r = 0; r < 4; ++r) {
        const int t = ti * 4 + r;
        const float lct = logc_s[t];
#pragma unroll
        for (int cc = 0; cc < 4; ++cc) {
            const int s = tj * 4 + cc;
            float w = (s <= t) ? expf(lct - logc_s[s]) * b_s[s] : 0.f;
            At[t][s] = w * acc_a[r][cc];
        }
    }

    // ---- inter-chunk: o = q @ S_c, ping-pong halves of Bf (T14) ----
    float o[4][8] = {};
    const float* Sbase = Sstates + (bh * NCHUNK + c) * 16384;
    const int tj8sw = swz8(tj * 8);
    const int rws = tid >> 4;
    const int cl = (tid & 15) * 8;
    const int sw = swz8(cl);
    float* Sb0 = Bf;
    float* Sb1 = Bf + 2112;   // 16 rows * 132
    {
        __syncthreads();   // all K_T reads of Bf done
        const float4* sp = (const float4*)(Sbase + (size_t)rws * 128 + cl);
        *(float4*)(&Sb0[rws * 132 + sw]) = sp[0];
        *(float4*)(&Sb0[rws * 132 + sw + 4]) = sp[1];
        __syncthreads();
    }
    for (int kb = 0; kb < 8; ++kb) {
        const float* src = (kb & 1) ? Sb1 : Sb0;
        float* dst = (kb & 1) ? Sb0 : Sb1;
        float4 nv0, nv1;
        if (kb < 7) {   // issue next-chunk loads BEFORE compute (hide latency)
            const float4* sp = (const float4*)(Sbase + (size_t)((kb + 1) * 16 + rws) * 128 + cl);
            nv0 = sp[0]; nv1 = sp[1];
        }
#pragma unroll
        for (int kk = 0; kk < 16; ++kk) {
            float a[4];
#pragma unroll
            for (int r = 0; r < 4; ++r) a[r] = Q_lds[ti * 4 + r][kb * 16 + kk];
            float4 s0 = *(const float4*)(&src[kk * 132 + tj8sw]);
            float4 s1 = *(const float4*)(&src[kk * 132 + tj8sw + 4]);
            float sv[8] = {s0.x, s0.y, s0.z, s0.w, s1.x, s1.y, s1.z, s1.w};
#pragma unroll
            for (int r = 0; r < 4; ++r)
#pragma unroll
                for (int j = 0; j < 8; ++j)
                    o[r][j] = fmaf(a[r], sv[j], o[r][j]);
        }
        if (kb < 7) {   // write-late into the other half
            *(float4*)(&dst[rws * 132 + sw]) = nv0;
            *(float4*)(&dst[rws * 132 + sw + 4]) = nv1;
        }
        __syncthreads();
    }
#pragma unroll
    for (int r = 0; r < 4; ++r) {
        const float ct = expf(logc_s[ti * 4 + r]);
#pragma unroll
        for (int j = 0; j < 8; ++j) o[r][j] *= ct;
    }

    for (int sh = 0; sh < 2; ++sh) {
        __syncthreads();
        {
            const int rr = tid >> 3;
            const int c0 = (tid & 7) * 16;
            const float4* vp = (const float4*)(vv + (size_t)(row0 + sh * 32 + rr) * 2048 + h * 128 + c0);
#pragma unroll
            for (int u = 0; u < 4; ++u) {
                const int clv = c0 + u * 4;
                *(float4*)(&Bf[rr * 132 + swz8(clv)]) = vp[u];
            }
        }
        __syncthreads();
#pragma unroll 2
        for (int sp = 0; sp < 32; ++sp) {
            const int s = sh * 32 + sp;
            float a[4];
#pragma unroll
            for (int r = 0; r < 4; ++r) a[r] = At[ti * 4 + r][s];
            float4 v0 = *(const float4*)(&Bf[sp * 132 + tj8sw]);
            float4 v1 = *(const float4*)(&Bf[sp * 132 + tj8sw + 4]);
            float vf[8] = {v0.x, v0.y, v0.z, v0.w, v1.x, v1.y, v1.z, v1.w};
#pragma unroll
            for (int r = 0; r < 4; ++r)
#pragma unroll
                for (int j = 0; j < 8; ++j)
                    o[r][j] = fmaf(a[r], vf[j], o[r][j]);
        }
    }

#pragma unroll
    for (int r = 0; r < 4; ++r) {
        float ss = 0.f;
#pragma unroll
        for (int j = 0; j < 8; ++j) ss = fmaf(o[r][j], o[r][j], ss);
        ss += __shfl_xor(ss, 1);
        ss += __shfl_xor(ss, 2);
        ss += __shfl_xor(ss, 4);
        ss += __shfl_xor(ss, 8);
        const float scale = rsqrtf(ss * (1.f / 128.f) + 1e-6f);
        const int t = ti * 4 + r;
        const float* zp = zbuf + (size_t)(row0 + t) * 2048 + h * 128 + tj * 8;
        unsigned short* gp = gated_b + (size_t)(row0 + t) * 2048 + h * 128 + tj * 8;
#pragma unroll
        for (int j = 0; j < 8; ++j) {
            float zv = zp[j];
            float g = o[r][j] * scale * norm_w[tj * 8 + j] * (1.f / (1.f + expf(-zv)));
            gp[j] = f2bf(g);
        }
    }
}

extern "C" void kernel_launch(void* const* d_in, const int* in_sizes, int n_in,
                              void* d_out, int out_size, void* d_ws, size_t ws_size,
                              hipStream_t stream) {
    (void)in_sizes; (void)n_in; (void)out_size; (void)ws_size;
    const float* x          = (const float*)d_in[0];
    const int*   input_pos  = (const int*)d_in[1];
    const float* W_qkvz     = (const float*)d_in[2];
    const float* W_b        = (const float*)d_in[3];
    const float* W_a        = (const float*)d_in[4];
    const float* conv_w     = (const float*)d_in[5];
    const float* norm_w     = (const float*)d_in[6];
    const float* W_out      = (const float*)d_in[7];
    const float* conv_state = (const float*)d_in[8];
    const float* rec_state  = (const float*)d_in[9];
    float* out = (float*)d_out;
    float* ws  = (float*)d_ws;

    // workspace (float elems), peak 232.75 MiB with phase-based aliasing:
    float* qkv   = ws;                                 // 25,165,824 f (phase 2-3)
    float* Mbuf  = ws;                                 // 16,777,216 f (phase 4+, aliases qkv)
    unsigned short* gated_b = (unsigned short*)(ws + 16777216); // bf16 (phase 5+)
    float* qn    = ws + 25165824ull;                   // 8,388,608 f (phase 3+)
    float* kn    = qn + 8388608ull;
    float* vv    = kn + 8388608ull;
    unsigned short* xb  = (unsigned short*)qn;         // phase 1-2, aliases qn
    unsigned short* WqT = (unsigned short*)(qn + 4194304ull); // 8192x2048 bf16
    float* zbuf  = vv + 8388608ull;
    unsigned short* WoT = (unsigned short*)(zbuf + 8388608ull);
    float* alpha = zbuf + 8388608ull + 2097152ull;
    float* beta  = alpha + 65536ull;
    float* logc  = beta + 65536ull;

    // 0. weight transposes (merged) + alpha/beta (also emits xb = bf16(x))
    transpose_cast2<<<dim3(256, 64, 2), 256, 0, stream>>>(W_qkvz, WqT, W_out, WoT);
    ab_kernel<<<512, 256, 0, stream>>>(x, W_b, W_a, beta, alpha, xb);

    // 1. merged qkvz GEMM: cols<6144 -> qkv (ldc 6144), cols>=6144 -> zbuf
    gemm256<<<dim3(8192 / 256, Mrows / 256), 512, 0, stream>>>(
        xb, WqT, qkv, zbuf, 2048, 2048, 2048);
    // 3. conv + silu + l2norm (last reader of qkv buffer)
    conv_kernel<<<dim3(Tt / 16, 48, Bb), 128, 0, stream>>>(
        qkv, conv_w, conv_state, input_pos, qn, kn, vv);
    // 4a. per-chunk prep: log-cumsum + M_c  (overwrites dead qkv region)
    chunk_prep<<<dim3(NCHUNK, Hh, Bb), 256, 0, stream>>>(
        kn, vv, alpha, beta, logc, Mbuf);
    // 4b. chunk-state recurrence, element-parallel (Mbuf -> Sstates in place)
    state_scan<<<2048, 256, 0, stream>>>(Mbuf, logc, rec_state, input_pos);
    // 4c. per-chunk outputs + RMSNorm + gate -> gated_b (bf16)
    chunk_out<<<dim3(NCHUNK, Hh, Bb), 256, 0, stream>>>(
        qn, kn, vv, beta, logc, Mbuf, norm_w, zbuf, gated_b);
    // 5. out = gated @ W_out   (MFMA bf16, 4-deep pipelined 128^2)
    gemm_bf16<<<dim3(2048 / 128, Mrows / 128), 256, 0, stream>>>(
        gated_b, WoT, out, 2048, 2048, 2048, 2048);
}

// Round 16
// 510.783 us; speedup vs baseline: 1.0192x; 1.0192x over previous
//
#include <hip/hip_runtime.h>
#include <hip/hip_bf16.h>
#include <math.h>

#define Bb 2
#define Tt 2048
#define Cc 2048
#define Hh 16
#define CONVD 6144
#define Mrows 4096  // B*T
#define NCHUNK 32   // T / 64

typedef __attribute__((ext_vector_type(8))) short short8v;
typedef __attribute__((ext_vector_type(4))) float floatx4;

__device__ __forceinline__ unsigned short f2bf(float f) {
    __hip_bfloat16 h = __float2bfloat16(f);
    return __builtin_bit_cast(unsigned short, h);
}

__device__ __forceinline__ void load_lds16(const void* g, void* l) {
    __builtin_amdgcn_global_load_lds(
        (const __attribute__((address_space(1))) void*)g,
        (__attribute__((address_space(3))) void*)l, 16, 0, 0);
}

// col-swizzle for float LDS tiles with 128-col rows read as float4 at tj*8:
__device__ __forceinline__ int swz8(int col) {
    return col ^ (((col >> 5) & 3) << 3);
}

#define LGKM0 asm volatile("s_waitcnt lgkmcnt(0)" ::: "memory")
#define VMC8  asm volatile("s_waitcnt vmcnt(8)" ::: "memory")
#define VMC4  asm volatile("s_waitcnt vmcnt(4)" ::: "memory")
#define VMC0  asm volatile("s_waitcnt vmcnt(0)" ::: "memory")
#define SCHB  __builtin_amdgcn_sched_barrier(0)
#define SBAR  __builtin_amdgcn_s_barrier()

// ------ merged transpose+cast: W1(2048x8192)->WT1, W2(2048x2048)->WT2 -------
__global__ __launch_bounds__(256) void transpose_cast2(
    const float* __restrict__ W1, unsigned short* __restrict__ WT1,
    const float* __restrict__ W2, unsigned short* __restrict__ WT2)
{
    const float* W; unsigned short* WT; int Nn;
    if (blockIdx.z == 0) { W = W1; WT = WT1; Nn = 8192; }
    else                 { W = W2; WT = WT2; Nn = 2048; if (blockIdx.x >= 64) return; }
    __shared__ float tile[32][33];
    const int n0 = blockIdx.x * 32;
    const int k0 = blockIdx.y * 32;
    const int tx = threadIdx.x & 31;
    const int ty = threadIdx.x >> 5;
#pragma unroll
    for (int r = ty; r < 32; r += 8)
        tile[r][tx] = W[(size_t)(k0 + r) * Nn + n0 + tx];
    __syncthreads();
#pragma unroll
    for (int r = ty; r < 32; r += 8)
        WT[(size_t)(n0 + r) * 2048 + k0 + tx] = f2bf(tile[tx][r]);
}

// ====== 256x256 bf16 MFMA GEMM, 4-deep counted-vmcnt pipeline (T1/2/4/5) ====
// EXACT r10 schedule (verified 142.6us/43.9% -- best of 6 schedule variants):
// frag ds_reads -> STG(t+3) -> lgkmcnt(0)+sched_barrier -> 32 MFMA ->
// counted vmcnt(8) -> s_barrier. Phase-split variants (r9/r13/r15) and
// fence removal (r11) all regress at this 1-block/CU 8-wave geometry.
__global__ __launch_bounds__(512) void gemm256(
    const unsigned short* __restrict__ A, const unsigned short* __restrict__ Bt,
    float* __restrict__ C1, float* __restrict__ C2,
    int Kk, int lda, int ldb)
{
    __shared__ __align__(16) unsigned short A_lds[4][256 * 32];
    __shared__ __align__(16) unsigned short B_lds[4][256 * 32];

    const int tid  = threadIdx.x;
    const int wid  = tid >> 6;            // 0..7
    const int lane = tid & 63;
    const int wr = wid >> 2, wc = wid & 3;
    const int l15 = lane & 15, kq = lane >> 4;

    const int rr = lane >> 2;
    const int cs = (lane & 3) ^ ((rr >> 1) & 3);
    const int fch = (kq ^ ((l15 >> 1) & 3)) << 3;   // in shorts

    // 8x8 super-chunk per XCD (grid 32x16, 512 blocks, bijective)
    const int bid = blockIdx.y * 32 + blockIdx.x;
    const int xcd = bid & 7;
    const int idx = bid >> 3;
    const int block_m = ((xcd >> 2) * 8 + (idx >> 3)) * 256;
    const int block_n = ((xcd & 3) * 8 + (idx & 7)) * 256;

    const unsigned short* Ag = A + (size_t)block_m * lda;
    const unsigned short* Bg = Bt + (size_t)block_n * ldb;

    const int NT = Kk >> 5;               // K-tiles of 32

#define STG(bi, kk0) do {                                                    \
    unsigned short* la_ = &A_lds[(bi)][0];                                   \
    unsigned short* lb_ = &B_lds[(bi)][0];                                   \
    _Pragma("unroll")                                                        \
    for (int j_ = 0; j_ < 2; ++j_) {                                         \
        const int brow = wid * 32 + j_ * 16;                                 \
        load_lds16(Ag + (size_t)(brow + rr) * lda + (kk0) + cs * 8,          \
                   la_ + brow * 32);                                         \
        load_lds16(Bg + (size_t)(brow + rr) * ldb + (kk0) + cs * 8,          \
                   lb_ + brow * 32);                                         \
    }                                                                        \
} while (0)

    floatx4 acc[8][4] = {};

    // prologue: stage tiles 0,1,2 (12 loads/wave), wait tile0, sync
    STG(0, 0);
    STG(1, 32);
    STG(2, 64);
    VMC8; SCHB; SBAR;

    for (int t = 0; t < NT; ++t) {
        const unsigned short* la = &A_lds[t & 3][0];
        const unsigned short* lb = &B_lds[t & 3][0];

        short8v af[8], bf[4];
#pragma unroll
        for (int mf = 0; mf < 8; ++mf)
            af[mf] = *(const short8v*)(la + (wr * 128 + mf * 16 + l15) * 32 + fch);
#pragma unroll
        for (int nf = 0; nf < 4; ++nf)
            bf[nf] = *(const short8v*)(lb + (wc * 64 + nf * 16 + l15) * 32 + fch);

        if (t + 3 < NT) STG((t + 3) & 3, (t + 3) << 5);

        LGKM0; SCHB;
        __builtin_amdgcn_s_setprio(1);
#pragma unroll
        for (int mf = 0; mf < 8; ++mf)
#pragma unroll
            for (int nf = 0; nf < 4; ++nf)
                acc[mf][nf] = __builtin_amdgcn_mfma_f32_16x16x32_bf16(
                    af[mf], bf[nf], acc[mf][nf], 0, 0, 0);
        __builtin_amdgcn_s_setprio(0);
        SCHB;
        if (t + 1 < NT) {
            if      (t + 3 < NT) { VMC8; }   // t+1 landed; t+2,t+3 in flight
            else if (t + 2 < NT) { VMC4; }
            else                 { VMC0; }
            SCHB; SBAR;
        }
    }
#undef STG

    // C-write, split per block column (uniform per block)
    float* Cp; int col0; size_t ldc;
    if (block_n < 6144) { Cp = C1; col0 = block_n;        ldc = 6144; }
    else                { Cp = C2; col0 = block_n - 6144; ldc = 2048; }
#pragma unroll
    for (int mf = 0; mf < 8; ++mf)
#pragma unroll
        for (int nf = 0; nf < 4; ++nf)
#pragma unroll
            for (int r = 0; r < 4; ++r) {
                int row = block_m + wr * 128 + mf * 16 + kq * 4 + r;
                int col = col0 + wc * 64 + nf * 16 + l15;
                Cp[(size_t)row * ldc + col] = acc[mf][nf][r];
            }
}

// ---- 128x128 bf16 MFMA GEMM, 4-deep counted-vmcnt pipeline (r10 pattern) ---
__global__ __launch_bounds__(256) void gemm_bf16(
    const unsigned short* __restrict__ A, const unsigned short* __restrict__ Bt,
    float* __restrict__ C, int Kk, int lda, int ldb, int ldc)
{
    __shared__ __align__(16) unsigned short A_lds[4][128 * 32];
    __shared__ __align__(16) unsigned short B_lds[4][128 * 32];

    const int tid = threadIdx.x;
    const int wid = tid >> 6;             // 0..3
    const int lane = tid & 63;
    const int wr = wid >> 1, wc = wid & 1;
    const int l15 = lane & 15, kq = lane >> 4;

    const int rr = lane >> 2;
    const int cs = (lane & 3) ^ ((rr >> 1) & 3);
    const int fch = (kq ^ ((l15 >> 1) & 3)) << 3;

    // m204 bijective XCD chunking (nwg % 8 == 0)
    const int nwg = gridDim.x * gridDim.y;
    const int bid = blockIdx.y * gridDim.x + blockIdx.x;
    const int wgid = (bid & 7) * (nwg >> 3) + (bid >> 3);
    const int block_m = (wgid / gridDim.x) * 128;
    const int block_n = (wgid % gridDim.x) * 128;

    const unsigned short* Ag = A + (size_t)block_m * lda;
    const unsigned short* Bg = Bt + (size_t)block_n * ldb;

    const int NT = Kk >> 5;

#define STG1(bi, kk0) do {                                                   \
    unsigned short* la_ = &A_lds[(bi)][0];                                   \
    unsigned short* lb_ = &B_lds[(bi)][0];                                   \
    _Pragma("unroll")                                                        \
    for (int j_ = 0; j_ < 2; ++j_) {                                         \
        const int brow = wid * 32 + j_ * 16;                                 \
        load_lds16(Ag + (size_t)(brow + rr) * lda + (kk0) + cs * 8,          \
                   la_ + brow * 32);                                         \
        load_lds16(Bg + (size_t)(brow + rr) * ldb + (kk0) + cs * 8,          \
                   lb_ + brow * 32);                                         \
    }                                                                        \
} while (0)

    floatx4 acc[4][4] = {};

    STG1(0, 0);
    STG1(1, 32);
    STG1(2, 64);
    VMC8; SCHB; SBAR;

    for (int t = 0; t < NT; ++t) {
        const unsigned short* la = &A_lds[t & 3][0];
        const unsigned short* lb = &B_lds[t & 3][0];

        short8v af[4], bf[4];
#pragma unroll
        for (int mf = 0; mf < 4; ++mf)
            af[mf] = *(const short8v*)(la + (wr * 64 + mf * 16 + l15) * 32 + fch);
#pragma unroll
        for (int nf = 0; nf < 4; ++nf)
            bf[nf] = *(const short8v*)(lb + (wc * 64 + nf * 16 + l15) * 32 + fch);

        if (t + 3 < NT) STG1((t + 3) & 3, (t + 3) << 5);

        LGKM0; SCHB;
        __builtin_amdgcn_s_setprio(1);
#pragma unroll
        for (int mf = 0; mf < 4; ++mf)
#pragma unroll
            for (int nf = 0; nf < 4; ++nf)
                acc[mf][nf] = __builtin_amdgcn_mfma_f32_16x16x32_bf16(
                    af[mf], bf[nf], acc[mf][nf], 0, 0, 0);
        __builtin_amdgcn_s_setprio(0);
        SCHB;
        if (t + 1 < NT) {
            if      (t + 3 < NT) { VMC8; }
            else if (t + 2 < NT) { VMC4; }
            else                 { VMC0; }
            SCHB; SBAR;
        }
    }
#undef STG1

#pragma unroll
    for (int mf = 0; mf < 4; ++mf)
#pragma unroll
        for (int nf = 0; nf < 4; ++nf)
#pragma unroll
            for (int r = 0; r < 4; ++r) {
                int row = block_m + wr * 64 + mf * 16 + kq * 4 + r;
                int col = block_n + wc * 64 + nf * 16 + l15;
                C[(size_t)row * ldc + col] = acc[mf][nf][r];
            }
}

// ---- alpha/beta: sigmoid(x @ W_{a,b}) + bf16 cast of x, LDS-row-shared -----
__global__ __launch_bounds__(256) void ab_kernel(
    const float* __restrict__ x, const float* __restrict__ W_b,
    const float* __restrict__ W_a, float* __restrict__ beta,
    float* __restrict__ alpha, unsigned short* __restrict__ xb)
{
    __shared__ float xs[8][2052];
    const int row0 = blockIdx.x * 8;
    const int tid = threadIdx.x;

#pragma unroll
    for (int it = 0; it < 16; ++it) {
        const int i = tid + it * 256;
        const int r = i >> 9;
        const int c4 = (i & 511) * 4;
        float4 v = *(const float4*)(x + (size_t)(row0 + r) * 2048 + c4);
        ushort4 ob;
        ob.x = f2bf(v.x); ob.y = f2bf(v.y); ob.z = f2bf(v.z); ob.w = f2bf(v.w);
        *(ushort4*)(xb + (size_t)(row0 + r) * 2048 + c4) = ob;
        *(float4*)(&xs[r][c4]) = v;
    }
    __syncthreads();

    const int mat = tid >> 7;
    const int r   = (tid >> 4) & 7;
    const int col = tid & 15;
    const float* W = mat ? W_a : W_b;
    float acc = 0.f;
#pragma unroll 8
    for (int k = 0; k < 2048; ++k)
        acc = fmaf(xs[r][k], W[(size_t)k * 16 + col], acc);
    float s = 1.f / (1.f + expf(-acc));
    float* outp = mat ? alpha : beta;
    outp[(size_t)(row0 + r) * 16 + col] = s;
}

// ------ conv(K=4) + SiLU + split + l2norm(q,k), float4-per-thread -----------
// block = 128 threads = 4 head-groups x 32 threads; each thread owns 4
// consecutive channels (16B loads/stores). l2norm: XOR butterfly over the
// 32-lane group (masks 1..16 stay within a 32-lane half) -> every lane gets
// the row total; normalize+store immediately (no LDS, single pass).
__global__ __launch_bounds__(128) void conv_kernel(
    const float* __restrict__ qkv, const float* __restrict__ conv_w,
    const float* __restrict__ conv_state, const int* __restrict__ input_pos,
    float* __restrict__ qn, float* __restrict__ kn, float* __restrict__ vv)
{
    const int tc = blockIdx.x;       // 0..127 (16 t each)
    const int hg = blockIdx.y;       // 0..11
    const int b  = blockIdx.z;
    const int tid = threadIdx.x;
    const int grp = tid >> 5;        // 0..3
    const int q4  = tid & 31;        // channel quad within head
    const int hs = hg * 4 + grp;     // 0..47
    const int kind = hs >> 4;        // 0=q,1=k,2=v
    const int h = hs & 15;
    const int c = kind * 2048 + h * 128 + q4 * 4;
    const int t0 = tc * 16;
    const float keep = (input_pos[0] == 0) ? 0.f : 1.f;

    float4 w4[4];
#pragma unroll
    for (int e = 0; e < 4; ++e)
        w4[e] = *(const float4*)(conv_w + (size_t)(c + e) * 4);

    float win[4][3];
#pragma unroll
    for (int e = 0; e < 4; ++e)
#pragma unroll
        for (int j = 0; j < 3; ++j) {
            int tau = t0 - 3 + j;
            win[e][j] = (tau >= 0)
                ? qkv[(size_t)(b * Tt + tau) * CONVD + c + e]
                : keep * conv_state[((size_t)b * CONVD + c + e) * 4 + (tau + 4)];
        }

    float* outbase = (kind == 0) ? qn : (kind == 1) ? kn : vv;

#pragma unroll 4
    for (int i = 0; i < 16; ++i) {
        float4 xv = *(const float4*)(qkv + (size_t)(b * Tt + t0 + i) * CONVD + c);
        float xs[4] = {xv.x, xv.y, xv.z, xv.w};
        float yy[4];
#pragma unroll
        for (int e = 0; e < 4; ++e) {
            float a = fmaf(w4[e].x, win[e][0],
                      fmaf(w4[e].y, win[e][1],
                      fmaf(w4[e].z, win[e][2], w4[e].w * xs[e])));
            yy[e] = a / (1.f + expf(-a));
            win[e][0] = win[e][1]; win[e][1] = win[e][2]; win[e][2] = xs[e];
        }
        float4 o;
        if (kind == 2) {
            o.x = yy[0]; o.y = yy[1]; o.z = yy[2]; o.w = yy[3];
        } else {
            float sq = yy[0]*yy[0] + yy[1]*yy[1] + yy[2]*yy[2] + yy[3]*yy[3];
            sq += __shfl_xor(sq, 1);
            sq += __shfl_xor(sq, 2);
            sq += __shfl_xor(sq, 4);
            sq += __shfl_xor(sq, 8);
            sq += __shfl_xor(sq, 16);
            float inv = 1.f / fmaxf(sqrtf(sq), 1e-12f);
            o.x = yy[0]*inv; o.y = yy[1]*inv; o.z = yy[2]*inv; o.w = yy[3]*inv;
        }
        *(float4*)(outbase + (size_t)(b * Tt + t0 + i) * 2048 + h * 128 + q4 * 4) = o;
    }
}

// ================= chunked scan, stage A: per-chunk prep =====================
__global__ __launch_bounds__(256) void chunk_prep(
    const float* __restrict__ kn, const float* __restrict__ vv,
    const float* __restrict__ alpha, const float* __restrict__ beta,
    float* __restrict__ logc_g, float* __restrict__ Mbuf)
{
    const int c = blockIdx.x, h = blockIdx.y, b = blockIdx.z;
    const int tid = threadIdx.x;
    const size_t bh = (size_t)b * Hh + h;

    __shared__ float K_lds[32][128];
    __shared__ float V_lds[32][128];
    __shared__ float logc_lds[64];
    __shared__ float b_lds[64];
    __shared__ float wk_lds[64];

    if (tid < 64) {
        const int row = b * Tt + c * 64 + tid;
        float a = alpha[(size_t)row * 16 + h];
        float la = logf(a);
#pragma unroll
        for (int d = 1; d < 64; d <<= 1) {
            float n = __shfl_up(la, d);
            if (tid >= d) la += n;
        }
        logc_lds[tid] = la;
        logc_g[bh * Tt + c * 64 + tid] = la;
        b_lds[tid] = beta[(size_t)row * 16 + h];
    }
    __syncthreads();
    if (tid < 64) {
        wk_lds[tid] = expf(logc_lds[63] - logc_lds[tid]) * b_lds[tid];
    }
    __syncthreads();

    const int ti = tid >> 4;
    const int tj = tid & 15;
    const int tj8sw = swz8(tj * 8);
    float acc[8][8];
#pragma unroll
    for (int i = 0; i < 8; ++i)
#pragma unroll
        for (int j = 0; j < 8; ++j) acc[i][j] = 0.f;

    for (int half = 0; half < 2; ++half) {
        {
            const int sl = tid >> 3;
            const int c0 = (tid & 7) * 16;
            const int grow = b * Tt + c * 64 + half * 32 + sl;
            const float4* kp = (const float4*)(kn + (size_t)grow * 2048 + h * 128 + c0);
            const float4* vp = (const float4*)(vv + (size_t)grow * 2048 + h * 128 + c0);
#pragma unroll
            for (int u = 0; u < 4; ++u) {
                const int cl = c0 + u * 4;
                *(float4*)(&K_lds[sl][cl]) = kp[u];
                *(float4*)(&V_lds[sl][swz8(cl)]) = vp[u];
            }
        }
        __syncthreads();
#pragma unroll 4
        for (int s = 0; s < 32; ++s) {
            float w = wk_lds[half * 32 + s];
            float4 k0 = *(const float4*)(&K_lds[s][ti * 8]);
            float4 k1 = *(const float4*)(&K_lds[s][ti * 8 + 4]);
            float4 v0 = *(const float4*)(&V_lds[s][tj8sw]);
            float4 v1 = *(const float4*)(&V_lds[s][tj8sw + 4]);
            float wk[8] = {w*k0.x, w*k0.y, w*k0.z, w*k0.w, w*k1.x, w*k1.y, w*k1.z, w*k1.w};
            float vf[8] = {v0.x, v0.y, v0.z, v0.w, v1.x, v1.y, v1.z, v1.w};
#pragma unroll
            for (int i = 0; i < 8; ++i)
#pragma unroll
                for (int j = 0; j < 8; ++j)
                    acc[i][j] = fmaf(wk[i], vf[j], acc[i][j]);
        }
        __syncthreads();
    }
    float* mb = Mbuf + ((bh * NCHUNK) + c) * 16384;
#pragma unroll
    for (int i = 0; i < 8; ++i) {
        float4 o0 = {acc[i][0], acc[i][1], acc[i][2], acc[i][3]};
        float4 o1 = {acc[i][4], acc[i][5], acc[i][6], acc[i][7]};
        *(float4*)(mb + (size_t)(ti * 8 + i) * 128 + tj * 8) = o0;
        *(float4*)(mb + (size_t)(ti * 8 + i) * 128 + tj * 8 + 4) = o1;
    }
}

// ================= chunked scan, stage B: state recurrence ==================
__global__ __launch_bounds__(256) void state_scan(
    float* __restrict__ Mbuf, const float* __restrict__ logc_g,
    const float* __restrict__ rec_state, const int* __restrict__ input_pos)
{
    const size_t g = (size_t)blockIdx.x * 256 + threadIdx.x;
    const int bh = (int)(g >> 14);
    const float keep = (input_pos[0] == 0) ? 0.f : 1.f;

    float S = keep * rec_state[g];
    const float* lc = logc_g + (size_t)bh * Tt;
    float* base = Mbuf + (size_t)(g & ~16383ull) * NCHUNK + (g & 16383);
#pragma unroll 4
    for (int c = 0; c < NCHUNK; ++c) {
        float Atot = expf(lc[c * 64 + 63]);
        float m = base[(size_t)c * 16384];
        base[(size_t)c * 16384] = S;
        S = fmaf(Atot, S, m);
    }
}

// ================= chunked scan, stage C: per-chunk output ==================
__global__ __launch_bounds__(256) void chunk_out(
    const float* __restrict__ qn, const float* __restrict__ kn,
    const float* __restrict__ vv, const float* __restrict__ beta,
    const float* __restrict__ logc_g, const float* __restrict__ Sstates,
    const float* __restrict__ norm_w, const float* __restrict__ zbuf,
    unsigned short* __restrict__ gated_b)
{
    const int c = blockIdx.x, h = blockIdx.y, b = blockIdx.z;
    const int tid = threadIdx.x;
    const int ti = tid >> 4;
    const int tj = tid & 15;
    const size_t bh = (size_t)b * Hh + h;
    const int row0 = b * Tt + c * 64;

    __shared__ float Q_lds[64][132];
    __shared__ float Bf[64 * 68];
    __shared__ float At[64][68];
    __shared__ float logc_s[64], b_s[64];

    {
        const int r = tid >> 2, c0 = (tid & 3) * 32;
        const float4* qp = (const float4*)(qn + (size_t)(row0 + r) * 2048 + h * 128 + c0);
#pragma unroll
        for (int u = 0; u < 8; ++u)
            *(float4*)(&Q_lds[r][c0 + u * 4]) = qp[u];
    }
    if (tid < 64) {
        logc_s[tid] = logc_g[bh * Tt + c * 64 + tid];
        b_s[tid] = beta[(size_t)(row0 + tid) * 16 + h];
    }

    float acc_a[4][4] = {};
    for (int kh = 0; kh < 2; ++kh) {
        __syncthreads();
        {
            const int s = tid >> 2, c0 = (tid & 3) * 16;
            const float* kp = kn + (size_t)(row0 + s) * 2048 + h * 128 + kh * 64 + c0;
#pragma unroll
            for (int u = 0; u < 16; ++u)
                Bf[(c0 + u) * 68 + s] = kp[u];
        }
        __syncthreads();
#pragma unroll 4
        for (int kk = 0; kk < 64; ++kk) {
            float a[4];
#pragma unroll
            for (int r = 0; r < 4; ++r) a[r] = Q_lds[ti * 4 + r][kh * 64 + kk];
            float4 bq = *(const float4*)(&Bf[kk * 68 + tj * 4]);
            float bb[4] = {bq.x, bq.y, bq.z, bq.w};
#pragma unroll
            for (int r = 0; r < 4; ++r)
#pragma unroll
                for (int cc = 0; cc < 4; ++cc)
                    acc_a[r][cc] = fmaf(a[r], bb[cc], acc_a[r][cc]);
        }
    }

#pragma unroll
    for (int r = 0; r < 4; ++r) {
        const int t = ti * 4 + r;
        const float lct = logc_s[t];
#pragma unroll
        for (int cc = 0; cc < 4; ++cc) {
            const int s = tj * 4 + cc;
            float w = (s <= t) ? expf(lct - logc_s[s]) * b_s[s] : 0.f;
            At[t][s] = w * acc_a[r][cc];
        }
    }

    // ---- inter-chunk: o = q @ S_c, ping-pong halves of Bf (T14) ----
    float o[4][8] = {};
    const float* Sbase = Sstates + (bh * NCHUNK + c) * 16384;
    const int tj8sw = swz8(tj * 8);
    const int rws = tid >> 4;
    const int cl = (tid & 15) * 8;
    const int sw = swz8(cl);
    float* Sb0 = Bf;
    float* Sb1 = Bf + 2112;   // 16 rows * 132
    {
        __syncthreads();   // all K_T reads of Bf done
        const float4* sp = (const float4*)(Sbase + (size_t)rws * 128 + cl);
        *(float4*)(&Sb0[rws * 132 + sw]) = sp[0];
        *(float4*)(&Sb0[rws * 132 + sw + 4]) = sp[1];
        __syncthreads();
    }
    for (int kb = 0; kb < 8; ++kb) {
        const float* src = (kb & 1) ? Sb1 : Sb0;
        float* dst = (kb & 1) ? Sb0 : Sb1;
        float4 nv0, nv1;
        if (kb < 7) {   // issue next-chunk loads BEFORE compute (hide latency)
            const float4* sp = (const float4*)(Sbase + (size_t)((kb + 1) * 16 + rws) * 128 + cl);
            nv0 = sp[0]; nv1 = sp[1];
        }
#pragma unroll
        for (int kk = 0; kk < 16; ++kk) {
            float a[4];
#pragma unroll
            for (int r = 0; r < 4; ++r) a[r] = Q_lds[ti * 4 + r][kb * 16 + kk];
            float4 s0 = *(const float4*)(&src[kk * 132 + tj8sw]);
            float4 s1 = *(const float4*)(&src[kk * 132 + tj8sw + 4]);
            float sv[8] = {s0.x, s0.y, s0.z, s0.w, s1.x, s1.y, s1.z, s1.w};
#pragma unroll
            for (int r = 0; r < 4; ++r)
#pragma unroll
                for (int j = 0; j < 8; ++j)
                    o[r][j] = fmaf(a[r], sv[j], o[r][j]);
        }
        if (kb < 7) {   // write-late into the other half
            *(float4*)(&dst[rws * 132 + sw]) = nv0;
            *(float4*)(&dst[rws * 132 + sw + 4]) = nv1;
        }
        __syncthreads();
    }
#pragma unroll
    for (int r = 0; r < 4; ++r) {
        const float ct = expf(logc_s[ti * 4 + r]);
#pragma unroll
        for (int j = 0; j < 8; ++j) o[r][j] *= ct;
    }

    for (int sh = 0; sh < 2; ++sh) {
        __syncthreads();
        {
            const int rr = tid >> 3;
            const int c0 = (tid & 7) * 16;
            const float4* vp = (const float4*)(vv + (size_t)(row0 + sh * 32 + rr) * 2048 + h * 128 + c0);
#pragma unroll
            for (int u = 0; u < 4; ++u) {
                const int clv = c0 + u * 4;
                *(float4*)(&Bf[rr * 132 + swz8(clv)]) = vp[u];
            }
        }
        __syncthreads();
#pragma unroll 2
        for (int sp = 0; sp < 32; ++sp) {
            const int s = sh * 32 + sp;
            float a[4];
#pragma unroll
            for (int r = 0; r < 4; ++r) a[r] = At[ti * 4 + r][s];
            float4 v0 = *(const float4*)(&Bf[sp * 132 + tj8sw]);
            float4 v1 = *(const float4*)(&Bf[sp * 132 + tj8sw + 4]);
            float vf[8] = {v0.x, v0.y, v0.z, v0.w, v1.x, v1.y, v1.z, v1.w};
#pragma unroll
            for (int r = 0; r < 4; ++r)
#pragma unroll
                for (int j = 0; j < 8; ++j)
                    o[r][j] = fmaf(a[r], vf[j], o[r][j]);
        }
    }

#pragma unroll
    for (int r = 0; r < 4; ++r) {
        float ss = 0.f;
#pragma unroll
        for (int j = 0; j < 8; ++j) ss = fmaf(o[r][j], o[r][j], ss);
        ss += __shfl_xor(ss, 1);
        ss += __shfl_xor(ss, 2);
        ss += __shfl_xor(ss, 4);
        ss += __shfl_xor(ss, 8);
        const float scale = rsqrtf(ss * (1.f / 128.f) + 1e-6f);
        const int t = ti * 4 + r;
        const float* zp = zbuf + (size_t)(row0 + t) * 2048 + h * 128 + tj * 8;
        unsigned short* gp = gated_b + (size_t)(row0 + t) * 2048 + h * 128 + tj * 8;
#pragma unroll
        for (int j = 0; j < 8; ++j) {
            float zv = zp[j];
            float g = o[r][j] * scale * norm_w[tj * 8 + j] * (1.f / (1.f + expf(-zv)));
            gp[j] = f2bf(g);
        }
    }
}

extern "C" void kernel_launch(void* const* d_in, const int* in_sizes, int n_in,
                              void* d_out, int out_size, void* d_ws, size_t ws_size,
                              hipStream_t stream) {
    (void)in_sizes; (void)n_in; (void)out_size; (void)ws_size;
    const float* x          = (const float*)d_in[0];
    const int*   input_pos  = (const int*)d_in[1];
    const float* W_qkvz     = (const float*)d_in[2];
    const float* W_b        = (const float*)d_in[3];
    const float* W_a        = (const float*)d_in[4];
    const float* conv_w     = (const float*)d_in[5];
    const float* norm_w     = (const float*)d_in[6];
    const float* W_out      = (const float*)d_in[7];
    const float* conv_state = (const float*)d_in[8];
    const float* rec_state  = (const float*)d_in[9];
    float* out = (float*)d_out;
    float* ws  = (float*)d_ws;

    // workspace (float elems), peak 232.75 MiB with phase-based aliasing:
    float* qkv   = ws;                                 // 25,165,824 f (phase 2-3)
    float* Mbuf  = ws;                                 // 16,777,216 f (phase 4+, aliases qkv)
    unsigned short* gated_b = (unsigned short*)(ws + 16777216); // bf16 (phase 5+)
    float* qn    = ws + 25165824ull;                   // 8,388,608 f (phase 3+)
    float* kn    = qn + 8388608ull;
    float* vv    = kn + 8388608ull;
    unsigned short* xb  = (unsigned short*)qn;         // phase 1-2, aliases qn
    unsigned short* WqT = (unsigned short*)(qn + 4194304ull); // 8192x2048 bf16
    float* zbuf  = vv + 8388608ull;
    unsigned short* WoT = (unsigned short*)(zbuf + 8388608ull);
    float* alpha = zbuf + 8388608ull + 2097152ull;
    float* beta  = alpha + 65536ull;
    float* logc  = beta + 65536ull;

    // 0. weight transposes (merged) + alpha/beta (also emits xb = bf16(x))
    transpose_cast2<<<dim3(256, 64, 2), 256, 0, stream>>>(W_qkvz, WqT, W_out, WoT);
    ab_kernel<<<512, 256, 0, stream>>>(x, W_b, W_a, beta, alpha, xb);

    // 1. merged qkvz GEMM: cols<6144 -> qkv (ldc 6144), cols>=6144 -> zbuf
    gemm256<<<dim3(8192 / 256, Mrows / 256), 512, 0, stream>>>(
        xb, WqT, qkv, zbuf, 2048, 2048, 2048);
    // 3. conv + silu + l2norm (last reader of qkv buffer)
    conv_kernel<<<dim3(Tt / 16, 12, Bb), 128, 0, stream>>>(
        qkv, conv_w, conv_state, input_pos, qn, kn, vv);
    // 4a. per-chunk prep: log-cumsum + M_c  (overwrites dead qkv region)
    chunk_prep<<<dim3(NCHUNK, Hh, Bb), 256, 0, stream>>>(
        kn, vv, alpha, beta, logc, Mbuf);
    // 4b. chunk-state recurrence, element-parallel (Mbuf -> Sstates in place)
    state_scan<<<2048, 256, 0, stream>>>(Mbuf, logc, rec_state, input_pos);
    // 4c. per-chunk outputs + RMSNorm + gate -> gated_b (bf16)
    chunk_out<<<dim3(NCHUNK, Hh, Bb), 256, 0, stream>>>(
        qn, kn, vv, beta, logc, Mbuf, norm_w, zbuf, gated_b);
    // 5. out = gated @ W_out   (MFMA bf16, 4-deep pipelined 128^2)
    gemm_bf16<<<dim3(2048 / 128, Mrows / 128), 256, 0, stream>>>(
        gated_b, WoT, out, 2048, 2048, 2048, 2048);
}

// Round 17
// 499.630 us; speedup vs baseline: 1.0419x; 1.0223x over previous
//
#include <hip/hip_runtime.h>
#include <hip/hip_bf16.h>
#include <math.h>

#define Bb 2
#define Tt 2048
#define Cc 2048
#define Hh 16
#define CONVD 6144
#define Mrows 4096  // B*T
#define NCHUNK 32   // T / 64

typedef __attribute__((ext_vector_type(8))) short short8v;
typedef __attribute__((ext_vector_type(4))) float floatx4;

__device__ __forceinline__ unsigned short f2bf(float f) {
    __hip_bfloat16 h = __float2bfloat16(f);
    return __builtin_bit_cast(unsigned short, h);
}

__device__ __forceinline__ void load_lds16(const void* g, void* l) {
    __builtin_amdgcn_global_load_lds(
        (const __attribute__((address_space(1))) void*)g,
        (__attribute__((address_space(3))) void*)l, 16, 0, 0);
}

// col-swizzle for float LDS tiles with 128-col rows read as float4 at tj*8:
__device__ __forceinline__ int swz8(int col) {
    return col ^ (((col >> 5) & 3) << 3);
}

#define LGKM0 asm volatile("s_waitcnt lgkmcnt(0)" ::: "memory")
#define VMC8  asm volatile("s_waitcnt vmcnt(8)" ::: "memory")
#define VMC4  asm volatile("s_waitcnt vmcnt(4)" ::: "memory")
#define VMC0  asm volatile("s_waitcnt vmcnt(0)" ::: "memory")
#define SCHB  __builtin_amdgcn_sched_barrier(0)
#define SBAR  __builtin_amdgcn_s_barrier()

// ------ merged transpose+cast: W1(2048x8192)->WT1, W2(2048x2048)->WT2 -------
// store side vectorized: each thread emits 4 consecutive k-values (ushort4).
__global__ __launch_bounds__(256) void transpose_cast2(
    const float* __restrict__ W1, unsigned short* __restrict__ WT1,
    const float* __restrict__ W2, unsigned short* __restrict__ WT2)
{
    const float* W; unsigned short* WT; int Nn;
    if (blockIdx.z == 0) { W = W1; WT = WT1; Nn = 8192; }
    else                 { W = W2; WT = WT2; Nn = 2048; if (blockIdx.x >= 64) return; }
    __shared__ float tile[32][33];
    const int n0 = blockIdx.x * 32;
    const int k0 = blockIdx.y * 32;
    const int tx = threadIdx.x & 31;
    const int ty = threadIdx.x >> 5;
#pragma unroll
    for (int r = ty; r < 32; r += 8)
        tile[r][tx] = W[(size_t)(k0 + r) * Nn + n0 + tx];
    __syncthreads();
    // store: thread -> (row = t>>3, k-quad = t&7); 8 lanes cover one 64B row seg
    const int row = threadIdx.x >> 3;
    const int cq  = (threadIdx.x & 7) * 4;
    ushort4 o;
    o.x = f2bf(tile[cq + 0][row]);
    o.y = f2bf(tile[cq + 1][row]);
    o.z = f2bf(tile[cq + 2][row]);
    o.w = f2bf(tile[cq + 3][row]);
    *(ushort4*)(WT + (size_t)(n0 + row) * 2048 + k0 + cq) = o;
}

// ====== 256x256 bf16 MFMA GEMM, 4-deep counted-vmcnt pipeline (T1/2/4/5) ====
// EXACT r10 schedule (verified 142.6us/43.9% -- best of 6 schedule variants):
// frag ds_reads -> STG(t+3) -> lgkmcnt(0)+sched_barrier -> 32 MFMA ->
// counted vmcnt(8) -> s_barrier.
__global__ __launch_bounds__(512) void gemm256(
    const unsigned short* __restrict__ A, const unsigned short* __restrict__ Bt,
    float* __restrict__ C1, float* __restrict__ C2,
    int Kk, int lda, int ldb)
{
    __shared__ __align__(16) unsigned short A_lds[4][256 * 32];
    __shared__ __align__(16) unsigned short B_lds[4][256 * 32];

    const int tid  = threadIdx.x;
    const int wid  = tid >> 6;            // 0..7
    const int lane = tid & 63;
    const int wr = wid >> 2, wc = wid & 3;
    const int l15 = lane & 15, kq = lane >> 4;

    const int rr = lane >> 2;
    const int cs = (lane & 3) ^ ((rr >> 1) & 3);
    const int fch = (kq ^ ((l15 >> 1) & 3)) << 3;   // in shorts

    // 8x8 super-chunk per XCD (grid 32x16, 512 blocks, bijective)
    const int bid = blockIdx.y * 32 + blockIdx.x;
    const int xcd = bid & 7;
    const int idx = bid >> 3;
    const int block_m = ((xcd >> 2) * 8 + (idx >> 3)) * 256;
    const int block_n = ((xcd & 3) * 8 + (idx & 7)) * 256;

    const unsigned short* Ag = A + (size_t)block_m * lda;
    const unsigned short* Bg = Bt + (size_t)block_n * ldb;

    const int NT = Kk >> 5;               // K-tiles of 32

#define STG(bi, kk0) do {                                                    \
    unsigned short* la_ = &A_lds[(bi)][0];                                   \
    unsigned short* lb_ = &B_lds[(bi)][0];                                   \
    _Pragma("unroll")                                                        \
    for (int j_ = 0; j_ < 2; ++j_) {                                         \
        const int brow = wid * 32 + j_ * 16;                                 \
        load_lds16(Ag + (size_t)(brow + rr) * lda + (kk0) + cs * 8,          \
                   la_ + brow * 32);                                         \
        load_lds16(Bg + (size_t)(brow + rr) * ldb + (kk0) + cs * 8,          \
                   lb_ + brow * 32);                                         \
    }                                                                        \
} while (0)

    floatx4 acc[8][4] = {};

    // prologue: stage tiles 0,1,2 (12 loads/wave), wait tile0, sync
    STG(0, 0);
    STG(1, 32);
    STG(2, 64);
    VMC8; SCHB; SBAR;

    for (int t = 0; t < NT; ++t) {
        const unsigned short* la = &A_lds[t & 3][0];
        const unsigned short* lb = &B_lds[t & 3][0];

        short8v af[8], bf[4];
#pragma unroll
        for (int mf = 0; mf < 8; ++mf)
            af[mf] = *(const short8v*)(la + (wr * 128 + mf * 16 + l15) * 32 + fch);
#pragma unroll
        for (int nf = 0; nf < 4; ++nf)
            bf[nf] = *(const short8v*)(lb + (wc * 64 + nf * 16 + l15) * 32 + fch);

        if (t + 3 < NT) STG((t + 3) & 3, (t + 3) << 5);

        LGKM0; SCHB;
        __builtin_amdgcn_s_setprio(1);
#pragma unroll
        for (int mf = 0; mf < 8; ++mf)
#pragma unroll
            for (int nf = 0; nf < 4; ++nf)
                acc[mf][nf] = __builtin_amdgcn_mfma_f32_16x16x32_bf16(
                    af[mf], bf[nf], acc[mf][nf], 0, 0, 0);
        __builtin_amdgcn_s_setprio(0);
        SCHB;
        if (t + 1 < NT) {
            if      (t + 3 < NT) { VMC8; }   // t+1 landed; t+2,t+3 in flight
            else if (t + 2 < NT) { VMC4; }
            else                 { VMC0; }
            SCHB; SBAR;
        }
    }
#undef STG

    // C-write, split per block column (uniform per block)
    float* Cp; int col0; size_t ldc;
    if (block_n < 6144) { Cp = C1; col0 = block_n;        ldc = 6144; }
    else                { Cp = C2; col0 = block_n - 6144; ldc = 2048; }
#pragma unroll
    for (int mf = 0; mf < 8; ++mf)
#pragma unroll
        for (int nf = 0; nf < 4; ++nf)
#pragma unroll
            for (int r = 0; r < 4; ++r) {
                int row = block_m + wr * 128 + mf * 16 + kq * 4 + r;
                int col = col0 + wc * 64 + nf * 16 + l15;
                Cp[(size_t)row * ldc + col] = acc[mf][nf][r];
            }
}

// ---- 128x128 bf16 MFMA GEMM, 4-deep counted-vmcnt pipeline (r10 pattern) ---
__global__ __launch_bounds__(256) void gemm_bf16(
    const unsigned short* __restrict__ A, const unsigned short* __restrict__ Bt,
    float* __restrict__ C, int Kk, int lda, int ldb, int ldc)
{
    __shared__ __align__(16) unsigned short A_lds[4][128 * 32];
    __shared__ __align__(16) unsigned short B_lds[4][128 * 32];

    const int tid = threadIdx.x;
    const int wid = tid >> 6;             // 0..3
    const int lane = tid & 63;
    const int wr = wid >> 1, wc = wid & 1;
    const int l15 = lane & 15, kq = lane >> 4;

    const int rr = lane >> 2;
    const int cs = (lane & 3) ^ ((rr >> 1) & 3);
    const int fch = (kq ^ ((l15 >> 1) & 3)) << 3;

    // m204 bijective XCD chunking (nwg % 8 == 0)
    const int nwg = gridDim.x * gridDim.y;
    const int bid = blockIdx.y * gridDim.x + blockIdx.x;
    const int wgid = (bid & 7) * (nwg >> 3) + (bid >> 3);
    const int block_m = (wgid / gridDim.x) * 128;
    const int block_n = (wgid % gridDim.x) * 128;

    const unsigned short* Ag = A + (size_t)block_m * lda;
    const unsigned short* Bg = Bt + (size_t)block_n * ldb;

    const int NT = Kk >> 5;

#define STG1(bi, kk0) do {                                                   \
    unsigned short* la_ = &A_lds[(bi)][0];                                   \
    unsigned short* lb_ = &B_lds[(bi)][0];                                   \
    _Pragma("unroll")                                                        \
    for (int j_ = 0; j_ < 2; ++j_) {                                         \
        const int brow = wid * 32 + j_ * 16;                                 \
        load_lds16(Ag + (size_t)(brow + rr) * lda + (kk0) + cs * 8,          \
                   la_ + brow * 32);                                         \
        load_lds16(Bg + (size_t)(brow + rr) * ldb + (kk0) + cs * 8,          \
                   lb_ + brow * 32);                                         \
    }                                                                        \
} while (0)

    floatx4 acc[4][4] = {};

    STG1(0, 0);
    STG1(1, 32);
    STG1(2, 64);
    VMC8; SCHB; SBAR;

    for (int t = 0; t < NT; ++t) {
        const unsigned short* la = &A_lds[t & 3][0];
        const unsigned short* lb = &B_lds[t & 3][0];

        short8v af[4], bf[4];
#pragma unroll
        for (int mf = 0; mf < 4; ++mf)
            af[mf] = *(const short8v*)(la + (wr * 64 + mf * 16 + l15) * 32 + fch);
#pragma unroll
        for (int nf = 0; nf < 4; ++nf)
            bf[nf] = *(const short8v*)(lb + (wc * 64 + nf * 16 + l15) * 32 + fch);

        if (t + 3 < NT) STG1((t + 3) & 3, (t + 3) << 5);

        LGKM0; SCHB;
        __builtin_amdgcn_s_setprio(1);
#pragma unroll
        for (int mf = 0; mf < 4; ++mf)
#pragma unroll
            for (int nf = 0; nf < 4; ++nf)
                acc[mf][nf] = __builtin_amdgcn_mfma_f32_16x16x32_bf16(
                    af[mf], bf[nf], acc[mf][nf], 0, 0, 0);
        __builtin_amdgcn_s_setprio(0);
        SCHB;
        if (t + 1 < NT) {
            if      (t + 3 < NT) { VMC8; }
            else if (t + 2 < NT) { VMC4; }
            else                 { VMC0; }
            SCHB; SBAR;
        }
    }
#undef STG1

#pragma unroll
    for (int mf = 0; mf < 4; ++mf)
#pragma unroll
        for (int nf = 0; nf < 4; ++nf)
#pragma unroll
            for (int r = 0; r < 4; ++r) {
                int row = block_m + wr * 64 + mf * 16 + kq * 4 + r;
                int col = block_n + wc * 64 + nf * 16 + l15;
                C[(size_t)row * ldc + col] = acc[mf][nf][r];
            }
}

// ---- alpha/beta: sigmoid(x @ W_{a,b}) + bf16 cast of x, LDS-row-shared -----
__global__ __launch_bounds__(256) void ab_kernel(
    const float* __restrict__ x, const float* __restrict__ W_b,
    const float* __restrict__ W_a, float* __restrict__ beta,
    float* __restrict__ alpha, unsigned short* __restrict__ xb)
{
    __shared__ float xs[8][2052];
    const int row0 = blockIdx.x * 8;
    const int tid = threadIdx.x;

#pragma unroll
    for (int it = 0; it < 16; ++it) {
        const int i = tid + it * 256;
        const int r = i >> 9;
        const int c4 = (i & 511) * 4;
        float4 v = *(const float4*)(x + (size_t)(row0 + r) * 2048 + c4);
        ushort4 ob;
        ob.x = f2bf(v.x); ob.y = f2bf(v.y); ob.z = f2bf(v.z); ob.w = f2bf(v.w);
        *(ushort4*)(xb + (size_t)(row0 + r) * 2048 + c4) = ob;
        *(float4*)(&xs[r][c4]) = v;
    }
    __syncthreads();

    const int mat = tid >> 7;
    const int r   = (tid >> 4) & 7;
    const int col = tid & 15;
    const float* W = mat ? W_a : W_b;
    float acc = 0.f;
#pragma unroll 8
    for (int k = 0; k < 2048; ++k)
        acc = fmaf(xs[r][k], W[(size_t)k * 16 + col], acc);
    float s = 1.f / (1.f + expf(-acc));
    float* outp = mat ? alpha : beta;
    outp[(size_t)(row0 + r) * 16 + col] = s;
}

// ------ conv(K=4) + SiLU + split + l2norm(q,k), float4-per-thread -----------
__global__ __launch_bounds__(128) void conv_kernel(
    const float* __restrict__ qkv, const float* __restrict__ conv_w,
    const float* __restrict__ conv_state, const int* __restrict__ input_pos,
    float* __restrict__ qn, float* __restrict__ kn, float* __restrict__ vv)
{
    const int tc = blockIdx.x;       // 0..127 (16 t each)
    const int hg = blockIdx.y;       // 0..11
    const int b  = blockIdx.z;
    const int tid = threadIdx.x;
    const int grp = tid >> 5;        // 0..3
    const int q4  = tid & 31;        // channel quad within head
    const int hs = hg * 4 + grp;     // 0..47
    const int kind = hs >> 4;        // 0=q,1=k,2=v
    const int h = hs & 15;
    const int c = kind * 2048 + h * 128 + q4 * 4;
    const int t0 = tc * 16;
    const float keep = (input_pos[0] == 0) ? 0.f : 1.f;

    float4 w4[4];
#pragma unroll
    for (int e = 0; e < 4; ++e)
        w4[e] = *(const float4*)(conv_w + (size_t)(c + e) * 4);

    float win[4][3];
#pragma unroll
    for (int e = 0; e < 4; ++e)
#pragma unroll
        for (int j = 0; j < 3; ++j) {
            int tau = t0 - 3 + j;
            win[e][j] = (tau >= 0)
                ? qkv[(size_t)(b * Tt + tau) * CONVD + c + e]
                : keep * conv_state[((size_t)b * CONVD + c + e) * 4 + (tau + 4)];
        }

    float* outbase = (kind == 0) ? qn : (kind == 1) ? kn : vv;

#pragma unroll 4
    for (int i = 0; i < 16; ++i) {
        float4 xv = *(const float4*)(qkv + (size_t)(b * Tt + t0 + i) * CONVD + c);
        float xs[4] = {xv.x, xv.y, xv.z, xv.w};
        float yy[4];
#pragma unroll
        for (int e = 0; e < 4; ++e) {
            float a = fmaf(w4[e].x, win[e][0],
                      fmaf(w4[e].y, win[e][1],
                      fmaf(w4[e].z, win[e][2], w4[e].w * xs[e])));
            yy[e] = a / (1.f + expf(-a));
            win[e][0] = win[e][1]; win[e][1] = win[e][2]; win[e][2] = xs[e];
        }
        float4 o;
        if (kind == 2) {
            o.x = yy[0]; o.y = yy[1]; o.z = yy[2]; o.w = yy[3];
        } else {
            float sq = yy[0]*yy[0] + yy[1]*yy[1] + yy[2]*yy[2] + yy[3]*yy[3];
            sq += __shfl_xor(sq, 1);
            sq += __shfl_xor(sq, 2);
            sq += __shfl_xor(sq, 4);
            sq += __shfl_xor(sq, 8);
            sq += __shfl_xor(sq, 16);
            float inv = 1.f / fmaxf(sqrtf(sq), 1e-12f);
            o.x = yy[0]*inv; o.y = yy[1]*inv; o.z = yy[2]*inv; o.w = yy[3]*inv;
        }
        *(float4*)(outbase + (size_t)(b * Tt + t0 + i) * 2048 + h * 128 + q4 * 4) = o;
    }
}

// ================= chunked scan, stage A: per-chunk prep =====================
__global__ __launch_bounds__(256) void chunk_prep(
    const float* __restrict__ kn, const float* __restrict__ vv,
    const float* __restrict__ alpha, const float* __restrict__ beta,
    float* __restrict__ logc_g, float* __restrict__ Mbuf)
{
    const int c = blockIdx.x, h = blockIdx.y, b = blockIdx.z;
    const int tid = threadIdx.x;
    const size_t bh = (size_t)b * Hh + h;

    __shared__ float K_lds[32][128];
    __shared__ float V_lds[32][128];
    __shared__ float logc_lds[64];
    __shared__ float b_lds[64];
    __shared__ float wk_lds[64];

    if (tid < 64) {
        const int row = b * Tt + c * 64 + tid;
        float a = alpha[(size_t)row * 16 + h];
        float la = logf(a);
#pragma unroll
        for (int d = 1; d < 64; d <<= 1) {
            float n = __shfl_up(la, d);
            if (tid >= d) la += n;
        }
        logc_lds[tid] = la;
        logc_g[bh * Tt + c * 64 + tid] = la;
        b_lds[tid] = beta[(size_t)row * 16 + h];
    }
    __syncthreads();
    if (tid < 64) {
        wk_lds[tid] = expf(logc_lds[63] - logc_lds[tid]) * b_lds[tid];
    }
    __syncthreads();

    const int ti = tid >> 4;
    const int tj = tid & 15;
    const int tj8sw = swz8(tj * 8);
    float acc[8][8];
#pragma unroll
    for (int i = 0; i < 8; ++i)
#pragma unroll
        for (int j = 0; j < 8; ++j) acc[i][j] = 0.f;

    for (int half = 0; half < 2; ++half) {
        {
            const int sl = tid >> 3;
            const int c0 = (tid & 7) * 16;
            const int grow = b * Tt + c * 64 + half * 32 + sl;
            const float4* kp = (const float4*)(kn + (size_t)grow * 2048 + h * 128 + c0);
            const float4* vp = (const float4*)(vv + (size_t)grow * 2048 + h * 128 + c0);
#pragma unroll
            for (int u = 0; u < 4; ++u) {
                const int cl = c0 + u * 4;
                *(float4*)(&K_lds[sl][cl]) = kp[u];
                *(float4*)(&V_lds[sl][swz8(cl)]) = vp[u];
            }
        }
        __syncthreads();
#pragma unroll 4
        for (int s = 0; s < 32; ++s) {
            float w = wk_lds[half * 32 + s];
            float4 k0 = *(const float4*)(&K_lds[s][ti * 8]);
            float4 k1 = *(const float4*)(&K_lds[s][ti * 8 + 4]);
            float4 v0 = *(const float4*)(&V_lds[s][tj8sw]);
            float4 v1 = *(const float4*)(&V_lds[s][tj8sw + 4]);
            float wk[8] = {w*k0.x, w*k0.y, w*k0.z, w*k0.w, w*k1.x, w*k1.y, w*k1.z, w*k1.w};
            float vf[8] = {v0.x, v0.y, v0.z, v0.w, v1.x, v1.y, v1.z, v1.w};
#pragma unroll
            for (int i = 0; i < 8; ++i)
#pragma unroll
                for (int j = 0; j < 8; ++j)
                    acc[i][j] = fmaf(wk[i], vf[j], acc[i][j]);
        }
        __syncthreads();
    }
    float* mb = Mbuf + ((bh * NCHUNK) + c) * 16384;
#pragma unroll
    for (int i = 0; i < 8; ++i) {
        float4 o0 = {acc[i][0], acc[i][1], acc[i][2], acc[i][3]};
        float4 o1 = {acc[i][4], acc[i][5], acc[i][6], acc[i][7]};
        *(float4*)(mb + (size_t)(ti * 8 + i) * 128 + tj * 8) = o0;
        *(float4*)(mb + (size_t)(ti * 8 + i) * 128 + tj * 8 + 4) = o1;
    }
}

// ================= chunked scan, stage B: state recurrence ==================
// float4 per thread: 131072 threads, 16B coalesced accesses over the
// 32-chunk serial walk (4x fewer dependent load/store chains than scalar).
__global__ __launch_bounds__(256) void state_scan(
    float* __restrict__ Mbuf, const float* __restrict__ logc_g,
    const float* __restrict__ rec_state, const int* __restrict__ input_pos)
{
    const size_t t4 = (size_t)blockIdx.x * 256 + threadIdx.x;  // 0..131071
    const int bh = (int)(t4 >> 12);
    const int ij4 = (int)(t4 & 4095) * 4;
    const float keep = (input_pos[0] == 0) ? 0.f : 1.f;

    float4 S = *(const float4*)(rec_state + t4 * 4);
    S.x *= keep; S.y *= keep; S.z *= keep; S.w *= keep;
    const float* lc = logc_g + (size_t)bh * Tt;
    float* base = Mbuf + (size_t)bh * NCHUNK * 16384 + ij4;
#pragma unroll 4
    for (int c = 0; c < NCHUNK; ++c) {
        float Atot = expf(lc[c * 64 + 63]);
        float4* p = (float4*)(base + (size_t)c * 16384);
        float4 m = *p;
        *p = S;
        S.x = fmaf(Atot, S.x, m.x);
        S.y = fmaf(Atot, S.y, m.y);
        S.z = fmaf(Atot, S.z, m.z);
        S.w = fmaf(Atot, S.w, m.w);
    }
}

// ================= chunked scan, stage C: per-chunk output ==================
__global__ __launch_bounds__(256) void chunk_out(
    const float* __restrict__ qn, const float* __restrict__ kn,
    const float* __restrict__ vv, const float* __restrict__ beta,
    const float* __restrict__ logc_g, const float* __restrict__ Sstates,
    const float* __restrict__ norm_w, const float* __restrict__ zbuf,
    unsigned short* __restrict__ gated_b)
{
    const int c = blockIdx.x, h = blockIdx.y, b = blockIdx.z;
    const int tid = threadIdx.x;
    const int ti = tid >> 4;
    const int tj = tid & 15;
    const size_t bh = (size_t)b * Hh + h;
    const int row0 = b * Tt + c * 64;

    __shared__ float Q_lds[64][132];
    __shared__ float Bf[64 * 68];
    __shared__ float At[64][68];
    __shared__ float logc_s[64], b_s[64];

    {
        const int r = tid >> 2, c0 = (tid & 3) * 32;
        const float4* qp = (const float4*)(qn + (size_t)(row0 + r) * 2048 + h * 128 + c0);
#pragma unroll
        for (int u = 0; u < 8; ++u)
            *(float4*)(&Q_lds[r][c0 + u * 4]) = qp[u];
    }
    if (tid < 64) {
        logc_s[tid] = logc_g[bh * Tt + c * 64 + tid];
        b_s[tid] = beta[(size_t)(row0 + tid) * 16 + h];
    }

    float acc_a[4][4] = {};
    for (int kh = 0; kh < 2; ++kh) {
        __syncthreads();
        {
            const int s = tid >> 2, c0 = (tid & 3) * 16;
            const float* kp = kn + (size_t)(row0 + s) * 2048 + h * 128 + kh * 64 + c0;
#pragma unroll
            for (int u = 0; u < 16; ++u)
                Bf[(c0 + u) * 68 + s] = kp[u];
        }
        __syncthreads();
#pragma unroll 4
        for (int kk = 0; kk < 64; ++kk) {
            float a[4];
#pragma unroll
            for (int r = 0; r < 4; ++r) a[r] = Q_lds[ti * 4 + r][kh * 64 + kk];
            float4 bq = *(const float4*)(&Bf[kk * 68 + tj * 4]);
            float bb[4] = {bq.x, bq.y, bq.z, bq.w};
#pragma unroll
            for (int r = 0; r < 4; ++r)
#pragma unroll
                for (int cc = 0; cc < 4; ++cc)
                    acc_a[r][cc] = fmaf(a[r], bb[cc], acc_a[r][cc]);
        }
    }

#pragma unroll
    for (int r = 0; r < 4; ++r) {
        const int t = ti * 4 + r;
        const float lct = logc_s[t];
#pragma unroll
        for (int cc = 0; cc < 4; ++cc) {
            const int s = tj * 4 + cc;
            float w = (s <= t) ? expf(lct - logc_s[s]) * b_s[s] : 0.f;
            At[t][s] = w * acc_a[r][cc];
        }
    }

    // ---- inter-chunk: o = q @ S_c, ping-pong halves of Bf (T14) ----
    float o[4][8] = {};
    const float* Sbase = Sstates + (bh * NCHUNK + c) * 16384;
    const int tj8sw = swz8(tj * 8);
    const int rws = tid >> 4;
    const int cl = (tid & 15) * 8;
    const int sw = swz8(cl);
    float* Sb0 = Bf;
    float* Sb1 = Bf + 2112;   // 16 rows * 132
    {
        __syncthreads();   // all K_T reads of Bf done
        const float4* sp = (const float4*)(Sbase + (size_t)rws * 128 + cl);
        *(float4*)(&Sb0[rws * 132 + sw]) = sp[0];
        *(float4*)(&Sb0[rws * 132 + sw + 4]) = sp[1];
        __syncthreads();
    }
    for (int kb = 0; kb < 8; ++kb) {
        const float* src = (kb & 1) ? Sb1 : Sb0;
        float* dst = (kb & 1) ? Sb0 : Sb1;
        float4 nv0, nv1;
        if (kb < 7) {   // issue next-chunk loads BEFORE compute (hide latency)
            const float4* sp = (const float4*)(Sbase + (size_t)((kb + 1) * 16 + rws) * 128 + cl);
            nv0 = sp[0]; nv1 = sp[1];
        }
#pragma unroll
        for (int kk = 0; kk < 16; ++kk) {
            float a[4];
#pragma unroll
            for (int r = 0; r < 4; ++r) a[r] = Q_lds[ti * 4 + r][kb * 16 + kk];
            float4 s0 = *(const float4*)(&src[kk * 132 + tj8sw]);
            float4 s1 = *(const float4*)(&src[kk * 132 + tj8sw + 4]);
            float sv[8] = {s0.x, s0.y, s0.z, s0.w, s1.x, s1.y, s1.z, s1.w};
#pragma unroll
            for (int r = 0; r < 4; ++r)
#pragma unroll
                for (int j = 0; j < 8; ++j)
                    o[r][j] = fmaf(a[r], sv[j], o[r][j]);
        }
        if (kb < 7) {   // write-late into the other half
            *(float4*)(&dst[rws * 132 + sw]) = nv0;
            *(float4*)(&dst[rws * 132 + sw + 4]) = nv1;
        }
        __syncthreads();
    }
#pragma unroll
    for (int r = 0; r < 4; ++r) {
        const float ct = expf(logc_s[ti * 4 + r]);
#pragma unroll
        for (int j = 0; j < 8; ++j) o[r][j] *= ct;
    }

    for (int sh = 0; sh < 2; ++sh) {
        __syncthreads();
        {
            const int rr = tid >> 3;
            const int c0 = (tid & 7) * 16;
            const float4* vp = (const float4*)(vv + (size_t)(row0 + sh * 32 + rr) * 2048 + h * 128 + c0);
#pragma unroll
            for (int u = 0; u < 4; ++u) {
                const int clv = c0 + u * 4;
                *(float4*)(&Bf[rr * 132 + swz8(clv)]) = vp[u];
            }
        }
        __syncthreads();
#pragma unroll 2
        for (int sp = 0; sp < 32; ++sp) {
            const int s = sh * 32 + sp;
            float a[4];
#pragma unroll
            for (int r = 0; r < 4; ++r) a[r] = At[ti * 4 + r][s];
            float4 v0 = *(const float4*)(&Bf[sp * 132 + tj8sw]);
            float4 v1 = *(const float4*)(&Bf[sp * 132 + tj8sw + 4]);
            float vf[8] = {v0.x, v0.y, v0.z, v0.w, v1.x, v1.y, v1.z, v1.w};
#pragma unroll
            for (int r = 0; r < 4; ++r)
#pragma unroll
                for (int j = 0; j < 8; ++j)
                    o[r][j] = fmaf(a[r], vf[j], o[r][j]);
        }
    }

#pragma unroll
    for (int r = 0; r < 4; ++r) {
        float ss = 0.f;
#pragma unroll
        for (int j = 0; j < 8; ++j) ss = fmaf(o[r][j], o[r][j], ss);
        ss += __shfl_xor(ss, 1);
        ss += __shfl_xor(ss, 2);
        ss += __shfl_xor(ss, 4);
        ss += __shfl_xor(ss, 8);
        const float scale = rsqrtf(ss * (1.f / 128.f) + 1e-6f);
        const int t = ti * 4 + r;
        const float* zp = zbuf + (size_t)(row0 + t) * 2048 + h * 128 + tj * 8;
        unsigned short* gp = gated_b + (size_t)(row0 + t) * 2048 + h * 128 + tj * 8;
#pragma unroll
        for (int j = 0; j < 8; ++j) {
            float zv = zp[j];
            float g = o[r][j] * scale * norm_w[tj * 8 + j] * (1.f / (1.f + expf(-zv)));
            gp[j] = f2bf(g);
        }
    }
}

extern "C" void kernel_launch(void* const* d_in, const int* in_sizes, int n_in,
                              void* d_out, int out_size, void* d_ws, size_t ws_size,
                              hipStream_t stream) {
    (void)in_sizes; (void)n_in; (void)out_size; (void)ws_size;
    const float* x          = (const float*)d_in[0];
    const int*   input_pos  = (const int*)d_in[1];
    const float* W_qkvz     = (const float*)d_in[2];
    const float* W_b        = (const float*)d_in[3];
    const float* W_a        = (const float*)d_in[4];
    const float* conv_w     = (const float*)d_in[5];
    const float* norm_w     = (const float*)d_in[6];
    const float* W_out      = (const float*)d_in[7];
    const float* conv_state = (const float*)d_in[8];
    const float* rec_state  = (const float*)d_in[9];
    float* out = (float*)d_out;
    float* ws  = (float*)d_ws;

    // workspace (float elems), peak 232.75 MiB with phase-based aliasing:
    float* qkv   = ws;                                 // 25,165,824 f (phase 2-3)
    float* Mbuf  = ws;                                 // 16,777,216 f (phase 4+, aliases qkv)
    unsigned short* gated_b = (unsigned short*)(ws + 16777216); // bf16 (phase 5+)
    float* qn    = ws + 25165824ull;                   // 8,388,608 f (phase 3+)
    float* kn    = qn + 8388608ull;
    float* vv    = kn + 8388608ull;
    unsigned short* xb  = (unsigned short*)qn;         // phase 1-2, aliases qn
    unsigned short* WqT = (unsigned short*)(qn + 4194304ull); // 8192x2048 bf16
    float* zbuf  = vv + 8388608ull;
    unsigned short* WoT = (unsigned short*)(zbuf + 8388608ull);
    float* alpha = zbuf + 8388608ull + 2097152ull;
    float* beta  = alpha + 65536ull;
    float* logc  = beta + 65536ull;

    // 0. weight transposes (merged) + alpha/beta (also emits xb = bf16(x))
    transpose_cast2<<<dim3(256, 64, 2), 256, 0, stream>>>(W_qkvz, WqT, W_out, WoT);
    ab_kernel<<<512, 256, 0, stream>>>(x, W_b, W_a, beta, alpha, xb);

    // 1. merged qkvz GEMM: cols<6144 -> qkv (ldc 6144), cols>=6144 -> zbuf
    gemm256<<<dim3(8192 / 256, Mrows / 256), 512, 0, stream>>>(
        xb, WqT, qkv, zbuf, 2048, 2048, 2048);
    // 3. conv + silu + l2norm (last reader of qkv buffer)
    conv_kernel<<<dim3(Tt / 16, 12, Bb), 128, 0, stream>>>(
        qkv, conv_w, conv_state, input_pos, qn, kn, vv);
    // 4a. per-chunk prep: log-cumsum + M_c  (overwrites dead qkv region)
    chunk_prep<<<dim3(NCHUNK, Hh, Bb), 256, 0, stream>>>(
        kn, vv, alpha, beta, logc, Mbuf);
    // 4b. chunk-state recurrence, float4-parallel (Mbuf -> Sstates in place)
    state_scan<<<512, 256, 0, stream>>>(Mbuf, logc, rec_state, input_pos);
    // 4c. per-chunk outputs + RMSNorm + gate -> gated_b (bf16)
    chunk_out<<<dim3(NCHUNK, Hh, Bb), 256, 0, stream>>>(
        qn, kn, vv, beta, logc, Mbuf, norm_w, zbuf, gated_b);
    // 5. out = gated @ W_out   (MFMA bf16, 4-deep pipelined 128^2)
    gemm_bf16<<<dim3(2048 / 128, Mrows / 128), 256, 0, stream>>>(
        gated_b, WoT, out, 2048, 2048, 2048, 2048);
}

// Round 18
// 497.084 us; speedup vs baseline: 1.0473x; 1.0051x over previous
//
#include <hip/hip_runtime.h>
#include <hip/hip_bf16.h>
#include <math.h>

#define Bb 2
#define Tt 2048
#define Cc 2048
#define Hh 16
#define CONVD 6144
#define Mrows 4096  // B*T
#define NCHUNK 32   // T / 64

typedef __attribute__((ext_vector_type(8))) short short8v;
typedef __attribute__((ext_vector_type(4))) float floatx4;

__device__ __forceinline__ unsigned short f2bf(float f) {
    __hip_bfloat16 h = __float2bfloat16(f);
    return __builtin_bit_cast(unsigned short, h);
}

__device__ __forceinline__ float bf2f(unsigned short u) {
    unsigned int x = ((unsigned int)u) << 16;
    return __builtin_bit_cast(float, x);
}

__device__ __forceinline__ void load_lds16(const void* g, void* l) {
    __builtin_amdgcn_global_load_lds(
        (const __attribute__((address_space(1))) void*)g,
        (__attribute__((address_space(3))) void*)l, 16, 0, 0);
}

// col-swizzle for float LDS tiles with 128-col rows read as float4 at tj*8:
__device__ __forceinline__ int swz8(int col) {
    return col ^ (((col >> 5) & 3) << 3);
}

#define LGKM0 asm volatile("s_waitcnt lgkmcnt(0)" ::: "memory")
#define VMC8  asm volatile("s_waitcnt vmcnt(8)" ::: "memory")
#define VMC4  asm volatile("s_waitcnt vmcnt(4)" ::: "memory")
#define VMC0  asm volatile("s_waitcnt vmcnt(0)" ::: "memory")
#define SCHB  __builtin_amdgcn_sched_barrier(0)
#define SBAR  __builtin_amdgcn_s_barrier()

// ------ merged transpose+cast: W1(2048x8192)->WT1, W2(2048x2048)->WT2 -------
__global__ __launch_bounds__(256) void transpose_cast2(
    const float* __restrict__ W1, unsigned short* __restrict__ WT1,
    const float* __restrict__ W2, unsigned short* __restrict__ WT2)
{
    const float* W; unsigned short* WT; int Nn;
    if (blockIdx.z == 0) { W = W1; WT = WT1; Nn = 8192; }
    else                 { W = W2; WT = WT2; Nn = 2048; if (blockIdx.x >= 64) return; }
    __shared__ float tile[32][33];
    const int n0 = blockIdx.x * 32;
    const int k0 = blockIdx.y * 32;
    const int tx = threadIdx.x & 31;
    const int ty = threadIdx.x >> 5;
#pragma unroll
    for (int r = ty; r < 32; r += 8)
        tile[r][tx] = W[(size_t)(k0 + r) * Nn + n0 + tx];
    __syncthreads();
    const int row = threadIdx.x >> 3;
    const int cq  = (threadIdx.x & 7) * 4;
    ushort4 o;
    o.x = f2bf(tile[cq + 0][row]);
    o.y = f2bf(tile[cq + 1][row]);
    o.z = f2bf(tile[cq + 2][row]);
    o.w = f2bf(tile[cq + 3][row]);
    *(ushort4*)(WT + (size_t)(n0 + row) * 2048 + k0 + cq) = o;
}

// ====== 256x256 bf16 MFMA GEMM, 4-deep counted-vmcnt pipeline (T1/2/4/5) ====
// EXACT r10 schedule (verified 142.6us/43.9%). C-write split: cols<6144 ->
// qkv (f32, ldc 6144); cols>=6144 -> z as BF16 (ldc 2048) -- z only feeds
// sigmoid (Lipschitz<=0.25) so bf16 storage is numerically negligible and
// cuts the z round-trip traffic in half.
__global__ __launch_bounds__(512) void gemm256(
    const unsigned short* __restrict__ A, const unsigned short* __restrict__ Bt,
    float* __restrict__ C1, unsigned short* __restrict__ C2b,
    int Kk, int lda, int ldb)
{
    __shared__ __align__(16) unsigned short A_lds[4][256 * 32];
    __shared__ __align__(16) unsigned short B_lds[4][256 * 32];

    const int tid  = threadIdx.x;
    const int wid  = tid >> 6;            // 0..7
    const int lane = tid & 63;
    const int wr = wid >> 2, wc = wid & 3;
    const int l15 = lane & 15, kq = lane >> 4;

    const int rr = lane >> 2;
    const int cs = (lane & 3) ^ ((rr >> 1) & 3);
    const int fch = (kq ^ ((l15 >> 1) & 3)) << 3;   // in shorts

    // 8x8 super-chunk per XCD (grid 32x16, 512 blocks, bijective)
    const int bid = blockIdx.y * 32 + blockIdx.x;
    const int xcd = bid & 7;
    const int idx = bid >> 3;
    const int block_m = ((xcd >> 2) * 8 + (idx >> 3)) * 256;
    const int block_n = ((xcd & 3) * 8 + (idx & 7)) * 256;

    const unsigned short* Ag = A + (size_t)block_m * lda;
    const unsigned short* Bg = Bt + (size_t)block_n * ldb;

    const int NT = Kk >> 5;               // K-tiles of 32

#define STG(bi, kk0) do {                                                    \
    unsigned short* la_ = &A_lds[(bi)][0];                                   \
    unsigned short* lb_ = &B_lds[(bi)][0];                                   \
    _Pragma("unroll")                                                        \
    for (int j_ = 0; j_ < 2; ++j_) {                                         \
        const int brow = wid * 32 + j_ * 16;                                 \
        load_lds16(Ag + (size_t)(brow + rr) * lda + (kk0) + cs * 8,          \
                   la_ + brow * 32);                                         \
        load_lds16(Bg + (size_t)(brow + rr) * ldb + (kk0) + cs * 8,          \
                   lb_ + brow * 32);                                         \
    }                                                                        \
} while (0)

    floatx4 acc[8][4] = {};

    // prologue: stage tiles 0,1,2 (12 loads/wave), wait tile0, sync
    STG(0, 0);
    STG(1, 32);
    STG(2, 64);
    VMC8; SCHB; SBAR;

    for (int t = 0; t < NT; ++t) {
        const unsigned short* la = &A_lds[t & 3][0];
        const unsigned short* lb = &B_lds[t & 3][0];

        short8v af[8], bf[4];
#pragma unroll
        for (int mf = 0; mf < 8; ++mf)
            af[mf] = *(const short8v*)(la + (wr * 128 + mf * 16 + l15) * 32 + fch);
#pragma unroll
        for (int nf = 0; nf < 4; ++nf)
            bf[nf] = *(const short8v*)(lb + (wc * 64 + nf * 16 + l15) * 32 + fch);

        if (t + 3 < NT) STG((t + 3) & 3, (t + 3) << 5);

        LGKM0; SCHB;
        __builtin_amdgcn_s_setprio(1);
#pragma unroll
        for (int mf = 0; mf < 8; ++mf)
#pragma unroll
            for (int nf = 0; nf < 4; ++nf)
                acc[mf][nf] = __builtin_amdgcn_mfma_f32_16x16x32_bf16(
                    af[mf], bf[nf], acc[mf][nf], 0, 0, 0);
        __builtin_amdgcn_s_setprio(0);
        SCHB;
        if (t + 1 < NT) {
            if      (t + 3 < NT) { VMC8; }   // t+1 landed; t+2,t+3 in flight
            else if (t + 2 < NT) { VMC4; }
            else                 { VMC0; }
            SCHB; SBAR;
        }
    }
#undef STG

    // C-write, split per block column (uniform per block)
    if (block_n < 6144) {
        float* Cp = C1; const int col0 = block_n; const size_t ldc = 6144;
#pragma unroll
        for (int mf = 0; mf < 8; ++mf)
#pragma unroll
            for (int nf = 0; nf < 4; ++nf)
#pragma unroll
                for (int r = 0; r < 4; ++r) {
                    int row = block_m + wr * 128 + mf * 16 + kq * 4 + r;
                    int col = col0 + wc * 64 + nf * 16 + l15;
                    Cp[(size_t)row * ldc + col] = acc[mf][nf][r];
                }
    } else {
        unsigned short* Cp = C2b; const int col0 = block_n - 6144;
        const size_t ldc = 2048;
#pragma unroll
        for (int mf = 0; mf < 8; ++mf)
#pragma unroll
            for (int nf = 0; nf < 4; ++nf)
#pragma unroll
                for (int r = 0; r < 4; ++r) {
                    int row = block_m + wr * 128 + mf * 16 + kq * 4 + r;
                    int col = col0 + wc * 64 + nf * 16 + l15;
                    Cp[(size_t)row * ldc + col] = f2bf(acc[mf][nf][r]);
                }
    }
}

// ---- 128x128 bf16 MFMA GEMM, 4-deep counted-vmcnt pipeline (r10 pattern) ---
__global__ __launch_bounds__(256) void gemm_bf16(
    const unsigned short* __restrict__ A, const unsigned short* __restrict__ Bt,
    float* __restrict__ C, int Kk, int lda, int ldb, int ldc)
{
    __shared__ __align__(16) unsigned short A_lds[4][128 * 32];
    __shared__ __align__(16) unsigned short B_lds[4][128 * 32];

    const int tid = threadIdx.x;
    const int wid = tid >> 6;             // 0..3
    const int lane = tid & 63;
    const int wr = wid >> 1, wc = wid & 1;
    const int l15 = lane & 15, kq = lane >> 4;

    const int rr = lane >> 2;
    const int cs = (lane & 3) ^ ((rr >> 1) & 3);
    const int fch = (kq ^ ((l15 >> 1) & 3)) << 3;

    // m204 bijective XCD chunking (nwg % 8 == 0)
    const int nwg = gridDim.x * gridDim.y;
    const int bid = blockIdx.y * gridDim.x + blockIdx.x;
    const int wgid = (bid & 7) * (nwg >> 3) + (bid >> 3);
    const int block_m = (wgid / gridDim.x) * 128;
    const int block_n = (wgid % gridDim.x) * 128;

    const unsigned short* Ag = A + (size_t)block_m * lda;
    const unsigned short* Bg = Bt + (size_t)block_n * ldb;

    const int NT = Kk >> 5;

#define STG1(bi, kk0) do {                                                   \
    unsigned short* la_ = &A_lds[(bi)][0];                                   \
    unsigned short* lb_ = &B_lds[(bi)][0];                                   \
    _Pragma("unroll")                                                        \
    for (int j_ = 0; j_ < 2; ++j_) {                                         \
        const int brow = wid * 32 + j_ * 16;                                 \
        load_lds16(Ag + (size_t)(brow + rr) * lda + (kk0) + cs * 8,          \
                   la_ + brow * 32);                                         \
        load_lds16(Bg + (size_t)(brow + rr) * ldb + (kk0) + cs * 8,          \
                   lb_ + brow * 32);                                         \
    }                                                                        \
} while (0)

    floatx4 acc[4][4] = {};

    STG1(0, 0);
    STG1(1, 32);
    STG1(2, 64);
    VMC8; SCHB; SBAR;

    for (int t = 0; t < NT; ++t) {
        const unsigned short* la = &A_lds[t & 3][0];
        const unsigned short* lb = &B_lds[t & 3][0];

        short8v af[4], bf[4];
#pragma unroll
        for (int mf = 0; mf < 4; ++mf)
            af[mf] = *(const short8v*)(la + (wr * 64 + mf * 16 + l15) * 32 + fch);
#pragma unroll
        for (int nf = 0; nf < 4; ++nf)
            bf[nf] = *(const short8v*)(lb + (wc * 64 + nf * 16 + l15) * 32 + fch);

        if (t + 3 < NT) STG1((t + 3) & 3, (t + 3) << 5);

        LGKM0; SCHB;
        __builtin_amdgcn_s_setprio(1);
#pragma unroll
        for (int mf = 0; mf < 4; ++mf)
#pragma unroll
            for (int nf = 0; nf < 4; ++nf)
                acc[mf][nf] = __builtin_amdgcn_mfma_f32_16x16x32_bf16(
                    af[mf], bf[nf], acc[mf][nf], 0, 0, 0);
        __builtin_amdgcn_s_setprio(0);
        SCHB;
        if (t + 1 < NT) {
            if      (t + 3 < NT) { VMC8; }
            else if (t + 2 < NT) { VMC4; }
            else                 { VMC0; }
            SCHB; SBAR;
        }
    }
#undef STG1

#pragma unroll
    for (int mf = 0; mf < 4; ++mf)
#pragma unroll
        for (int nf = 0; nf < 4; ++nf)
#pragma unroll
            for (int r = 0; r < 4; ++r) {
                int row = block_m + wr * 64 + mf * 16 + kq * 4 + r;
                int col = block_n + wc * 64 + nf * 16 + l15;
                C[(size_t)row * ldc + col] = acc[mf][nf][r];
            }
}

// ---- alpha/beta: sigmoid(x @ W_{a,b}) + bf16 cast of x, LDS-row-shared -----
__global__ __launch_bounds__(256) void ab_kernel(
    const float* __restrict__ x, const float* __restrict__ W_b,
    const float* __restrict__ W_a, float* __restrict__ beta,
    float* __restrict__ alpha, unsigned short* __restrict__ xb)
{
    __shared__ float xs[8][2052];
    const int row0 = blockIdx.x * 8;
    const int tid = threadIdx.x;

#pragma unroll
    for (int it = 0; it < 16; ++it) {
        const int i = tid + it * 256;
        const int r = i >> 9;
        const int c4 = (i & 511) * 4;
        float4 v = *(const float4*)(x + (size_t)(row0 + r) * 2048 + c4);
        ushort4 ob;
        ob.x = f2bf(v.x); ob.y = f2bf(v.y); ob.z = f2bf(v.z); ob.w = f2bf(v.w);
        *(ushort4*)(xb + (size_t)(row0 + r) * 2048 + c4) = ob;
        *(float4*)(&xs[r][c4]) = v;
    }
    __syncthreads();

    const int mat = tid >> 7;
    const int r   = (tid >> 4) & 7;
    const int col = tid & 15;
    const float* W = mat ? W_a : W_b;
    float acc = 0.f;
#pragma unroll 8
    for (int k = 0; k < 2048; ++k)
        acc = fmaf(xs[r][k], W[(size_t)k * 16 + col], acc);
    float s = 1.f / (1.f + expf(-acc));
    float* outp = mat ? alpha : beta;
    outp[(size_t)(row0 + r) * 16 + col] = s;
}

// ------ conv(K=4) + SiLU + split + l2norm(q,k), float4-per-thread -----------
__global__ __launch_bounds__(128) void conv_kernel(
    const float* __restrict__ qkv, const float* __restrict__ conv_w,
    const float* __restrict__ conv_state, const int* __restrict__ input_pos,
    float* __restrict__ qn, float* __restrict__ kn, float* __restrict__ vv)
{
    const int tc = blockIdx.x;       // 0..127 (16 t each)
    const int hg = blockIdx.y;       // 0..11
    const int b  = blockIdx.z;
    const int tid = threadIdx.x;
    const int grp = tid >> 5;        // 0..3
    const int q4  = tid & 31;        // channel quad within head
    const int hs = hg * 4 + grp;     // 0..47
    const int kind = hs >> 4;        // 0=q,1=k,2=v
    const int h = hs & 15;
    const int c = kind * 2048 + h * 128 + q4 * 4;
    const int t0 = tc * 16;
    const float keep = (input_pos[0] == 0) ? 0.f : 1.f;

    float4 w4[4];
#pragma unroll
    for (int e = 0; e < 4; ++e)
        w4[e] = *(const float4*)(conv_w + (size_t)(c + e) * 4);

    float win[4][3];
#pragma unroll
    for (int e = 0; e < 4; ++e)
#pragma unroll
        for (int j = 0; j < 3; ++j) {
            int tau = t0 - 3 + j;
            win[e][j] = (tau >= 0)
                ? qkv[(size_t)(b * Tt + tau) * CONVD + c + e]
                : keep * conv_state[((size_t)b * CONVD + c + e) * 4 + (tau + 4)];
        }

    float* outbase = (kind == 0) ? qn : (kind == 1) ? kn : vv;

#pragma unroll 4
    for (int i = 0; i < 16; ++i) {
        float4 xv = *(const float4*)(qkv + (size_t)(b * Tt + t0 + i) * CONVD + c);
        float xs[4] = {xv.x, xv.y, xv.z, xv.w};
        float yy[4];
#pragma unroll
        for (int e = 0; e < 4; ++e) {
            float a = fmaf(w4[e].x, win[e][0],
                      fmaf(w4[e].y, win[e][1],
                      fmaf(w4[e].z, win[e][2], w4[e].w * xs[e])));
            yy[e] = a / (1.f + expf(-a));
            win[e][0] = win[e][1]; win[e][1] = win[e][2]; win[e][2] = xs[e];
        }
        float4 o;
        if (kind == 2) {
            o.x = yy[0]; o.y = yy[1]; o.z = yy[2]; o.w = yy[3];
        } else {
            float sq = yy[0]*yy[0] + yy[1]*yy[1] + yy[2]*yy[2] + yy[3]*yy[3];
            sq += __shfl_xor(sq, 1);
            sq += __shfl_xor(sq, 2);
            sq += __shfl_xor(sq, 4);
            sq += __shfl_xor(sq, 8);
            sq += __shfl_xor(sq, 16);
            float inv = 1.f / fmaxf(sqrtf(sq), 1e-12f);
            o.x = yy[0]*inv; o.y = yy[1]*inv; o.z = yy[2]*inv; o.w = yy[3]*inv;
        }
        *(float4*)(outbase + (size_t)(b * Tt + t0 + i) * 2048 + h * 128 + q4 * 4) = o;
    }
}

// ================= chunked scan, stage A: per-chunk prep =====================
__global__ __launch_bounds__(256) void chunk_prep(
    const float* __restrict__ kn, const float* __restrict__ vv,
    const float* __restrict__ alpha, const float* __restrict__ beta,
    float* __restrict__ logc_g, float* __restrict__ Mbuf)
{
    const int c = blockIdx.x, h = blockIdx.y, b = blockIdx.z;
    const int tid = threadIdx.x;
    const size_t bh = (size_t)b * Hh + h;

    __shared__ float K_lds[32][128];
    __shared__ float V_lds[32][128];
    __shared__ float logc_lds[64];
    __shared__ float b_lds[64];
    __shared__ float wk_lds[64];

    if (tid < 64) {
        const int row = b * Tt + c * 64 + tid;
        float a = alpha[(size_t)row * 16 + h];
        float la = logf(a);
#pragma unroll
        for (int d = 1; d < 64; d <<= 1) {
            float n = __shfl_up(la, d);
            if (tid >= d) la += n;
        }
        logc_lds[tid] = la;
        logc_g[bh * Tt + c * 64 + tid] = la;
        b_lds[tid] = beta[(size_t)row * 16 + h];
    }
    __syncthreads();
    if (tid < 64) {
        wk_lds[tid] = expf(logc_lds[63] - logc_lds[tid]) * b_lds[tid];
    }
    __syncthreads();

    const int ti = tid >> 4;
    const int tj = tid & 15;
    const int tj8sw = swz8(tj * 8);
    float acc[8][8];
#pragma unroll
    for (int i = 0; i < 8; ++i)
#pragma unroll
        for (int j = 0; j < 8; ++j) acc[i][j] = 0.f;

    for (int half = 0; half < 2; ++half) {
        {
            const int sl = tid >> 3;
            const int c0 = (tid & 7) * 16;
            const int grow = b * Tt + c * 64 + half * 32 + sl;
            const float4* kp = (const float4*)(kn + (size_t)grow * 2048 + h * 128 + c0);
            const float4* vp = (const float4*)(vv + (size_t)grow * 2048 + h * 128 + c0);
#pragma unroll
            for (int u = 0; u < 4; ++u) {
                const int cl = c0 + u * 4;
                *(float4*)(&K_lds[sl][cl]) = kp[u];
                *(float4*)(&V_lds[sl][swz8(cl)]) = vp[u];
            }
        }
        __syncthreads();
#pragma unroll 4
        for (int s = 0; s < 32; ++s) {
            float w = wk_lds[half * 32 + s];
            float4 k0 = *(const float4*)(&K_lds[s][ti * 8]);
            float4 k1 = *(const float4*)(&K_lds[s][ti * 8 + 4]);
            float4 v0 = *(const float4*)(&V_lds[s][tj8sw]);
            float4 v1 = *(const float4*)(&V_lds[s][tj8sw + 4]);
            float wk[8] = {w*k0.x, w*k0.y, w*k0.z, w*k0.w, w*k1.x, w*k1.y, w*k1.z, w*k1.w};
            float vf[8] = {v0.x, v0.y, v0.z, v0.w, v1.x, v1.y, v1.z, v1.w};
#pragma unroll
            for (int i = 0; i < 8; ++i)
#pragma unroll
                for (int j = 0; j < 8; ++j)
                    acc[i][j] = fmaf(wk[i], vf[j], acc[i][j]);
        }
        __syncthreads();
    }
    float* mb = Mbuf + ((bh * NCHUNK) + c) * 16384;
#pragma unroll
    for (int i = 0; i < 8; ++i) {
        float4 o0 = {acc[i][0], acc[i][1], acc[i][2], acc[i][3]};
        float4 o1 = {acc[i][4], acc[i][5], acc[i][6], acc[i][7]};
        *(float4*)(mb + (size_t)(ti * 8 + i) * 128 + tj * 8) = o0;
        *(float4*)(mb + (size_t)(ti * 8 + i) * 128 + tj * 8 + 4) = o1;
    }
}

// ================= chunked scan, stage B: state recurrence ==================
__global__ __launch_bounds__(256) void state_scan(
    float* __restrict__ Mbuf, const float* __restrict__ logc_g,
    const float* __restrict__ rec_state, const int* __restrict__ input_pos)
{
    const size_t t4 = (size_t)blockIdx.x * 256 + threadIdx.x;  // 0..131071
    const int bh = (int)(t4 >> 12);
    const int ij4 = (int)(t4 & 4095) * 4;
    const float keep = (input_pos[0] == 0) ? 0.f : 1.f;

    float4 S = *(const float4*)(rec_state + t4 * 4);
    S.x *= keep; S.y *= keep; S.z *= keep; S.w *= keep;
    const float* lc = logc_g + (size_t)bh * Tt;
    float* base = Mbuf + (size_t)bh * NCHUNK * 16384 + ij4;
#pragma unroll 4
    for (int c = 0; c < NCHUNK; ++c) {
        float Atot = expf(lc[c * 64 + 63]);
        float4* p = (float4*)(base + (size_t)c * 16384);
        float4 m = *p;
        *p = S;
        S.x = fmaf(Atot, S.x, m.x);
        S.y = fmaf(Atot, S.y, m.y);
        S.z = fmaf(Atot, S.z, m.z);
        S.w = fmaf(Atot, S.w, m.w);
    }
}

// ================= chunked scan, stage C: per-chunk output ==================
// z read as bf16 (zb); otherwise identical to r17.
__global__ __launch_bounds__(256) void chunk_out(
    const float* __restrict__ qn, const float* __restrict__ kn,
    const float* __restrict__ vv, const float* __restrict__ beta,
    const float* __restrict__ logc_g, const float* __restrict__ Sstates,
    const float* __restrict__ norm_w, const unsigned short* __restrict__ zb,
    unsigned short* __restrict__ gated_b)
{
    const int c = blockIdx.x, h = blockIdx.y, b = blockIdx.z;
    const int tid = threadIdx.x;
    const int ti = tid >> 4;
    const int tj = tid & 15;
    const size_t bh = (size_t)b * Hh + h;
    const int row0 = b * Tt + c * 64;

    __shared__ float Q_lds[64][132];
    __shared__ float Bf[64 * 68];
    __shared__ float At[64][68];
    __shared__ float logc_s[64], b_s[64];

    {
        const int r = tid >> 2, c0 = (tid & 3) * 32;
        const float4* qp = (const float4*)(qn + (size_t)(row0 + r) * 2048 + h * 128 + c0);
#pragma unroll
        for (int u = 0; u < 8; ++u)
            *(float4*)(&Q_lds[r][c0 + u * 4]) = qp[u];
    }
    if (tid < 64) {
        logc_s[tid] = logc_g[bh * Tt + c * 64 + tid];
        b_s[tid] = beta[(size_t)(row0 + tid) * 16 + h];
    }

    float acc_a[4][4] = {};
    for (int kh = 0; kh < 2; ++kh) {
        __syncthreads();
        {
            const int s = tid >> 2, c0 = (tid & 3) * 16;
            const float* kp = kn + (size_t)(row0 + s) * 2048 + h * 128 + kh * 64 + c0;
#pragma unroll
            for (int u = 0; u < 16; ++u)
                Bf[(c0 + u) * 68 + s] = kp[u];
        }
        __syncthreads();
#pragma unroll 4
        for (int kk = 0; kk < 64; ++kk) {
            float a[4];
#pragma unroll
            for (int r = 0; r < 4; ++r) a[r] = Q_lds[ti * 4 + r][kh * 64 + kk];
            float4 bq = *(const float4*)(&Bf[kk * 68 + tj * 4]);
            float bb[4] = {bq.x, bq.y, bq.z, bq.w};
#pragma unroll
            for (int r = 0; r < 4; ++r)
#pragma unroll
                for (int cc = 0; cc < 4; ++cc)
                    acc_a[r][cc] = fmaf(a[r], bb[cc], acc_a[r][cc]);
        }
    }

#pragma unroll
    for (int r = 0; r < 4; ++r) {
        const int t = ti * 4 + r;
        const float lct = logc_s[t];
#pragma unroll
        for (int cc = 0; cc < 4; ++cc) {
            const int s = tj * 4 + cc;
            float w = (s <= t) ? expf(lct - logc_s[s]) * b_s[s] : 0.f;
            At[t][s] = w * acc_a[r][cc];
        }
    }

    // ---- inter-chunk: o = q @ S_c, ping-pong halves of Bf (T14) ----
    float o[4][8] = {};
    const float* Sbase = Sstates + (bh * NCHUNK + c) * 16384;
    const int tj8sw = swz8(tj * 8);
    const int rws = tid >> 4;
    const int cl = (tid & 15) * 8;
    const int sw = swz8(cl);
    float* Sb0 = Bf;
    float* Sb1 = Bf + 2112;   // 16 rows * 132
    {
        __syncthreads();   // all K_T reads of Bf done
        const float4* sp = (const float4*)(Sbase + (size_t)rws * 128 + cl);
        *(float4*)(&Sb0[rws * 132 + sw]) = sp[0];
        *(float4*)(&Sb0[rws * 132 + sw + 4]) = sp[1];
        __syncthreads();
    }
    for (int kb = 0; kb < 8; ++kb) {
        const float* src = (kb & 1) ? Sb1 : Sb0;
        float* dst = (kb & 1) ? Sb0 : Sb1;
        float4 nv0, nv1;
        if (kb < 7) {   // issue next-chunk loads BEFORE compute (hide latency)
            const float4* sp = (const float4*)(Sbase + (size_t)((kb + 1) * 16 + rws) * 128 + cl);
            nv0 = sp[0]; nv1 = sp[1];
        }
#pragma unroll
        for (int kk = 0; kk < 16; ++kk) {
            float a[4];
#pragma unroll
            for (int r = 0; r < 4; ++r) a[r] = Q_lds[ti * 4 + r][kb * 16 + kk];
            float4 s0 = *(const float4*)(&src[kk * 132 + tj8sw]);
            float4 s1 = *(const float4*)(&src[kk * 132 + tj8sw + 4]);
            float sv[8] = {s0.x, s0.y, s0.z, s0.w, s1.x, s1.y, s1.z, s1.w};
#pragma unroll
            for (int r = 0; r < 4; ++r)
#pragma unroll
                for (int j = 0; j < 8; ++j)
                    o[r][j] = fmaf(a[r], sv[j], o[r][j]);
        }
        if (kb < 7) {   // write-late into the other half
            *(float4*)(&dst[rws * 132 + sw]) = nv0;
            *(float4*)(&dst[rws * 132 + sw + 4]) = nv1;
        }
        __syncthreads();
    }
#pragma unroll
    for (int r = 0; r < 4; ++r) {
        const float ct = expf(logc_s[ti * 4 + r]);
#pragma unroll
        for (int j = 0; j < 8; ++j) o[r][j] *= ct;
    }

    for (int sh = 0; sh < 2; ++sh) {
        __syncthreads();
        {
            const int rr = tid >> 3;
            const int c0 = (tid & 7) * 16;
            const float4* vp = (const float4*)(vv + (size_t)(row0 + sh * 32 + rr) * 2048 + h * 128 + c0);
#pragma unroll
            for (int u = 0; u < 4; ++u) {
                const int clv = c0 + u * 4;
                *(float4*)(&Bf[rr * 132 + swz8(clv)]) = vp[u];
            }
        }
        __syncthreads();
#pragma unroll 2
        for (int sp = 0; sp < 32; ++sp) {
            const int s = sh * 32 + sp;
            float a[4];
#pragma unroll
            for (int r = 0; r < 4; ++r) a[r] = At[ti * 4 + r][s];
            float4 v0 = *(const float4*)(&Bf[sp * 132 + tj8sw]);
            float4 v1 = *(const float4*)(&Bf[sp * 132 + tj8sw + 4]);
            float vf[8] = {v0.x, v0.y, v0.z, v0.w, v1.x, v1.y, v1.z, v1.w};
#pragma unroll
            for (int r = 0; r < 4; ++r)
#pragma unroll
                for (int j = 0; j < 8; ++j)
                    o[r][j] = fmaf(a[r], vf[j], o[r][j]);
        }
    }

#pragma unroll
    for (int r = 0; r < 4; ++r) {
        float ss = 0.f;
#pragma unroll
        for (int j = 0; j < 8; ++j) ss = fmaf(o[r][j], o[r][j], ss);
        ss += __shfl_xor(ss, 1);
        ss += __shfl_xor(ss, 2);
        ss += __shfl_xor(ss, 4);
        ss += __shfl_xor(ss, 8);
        const float scale = rsqrtf(ss * (1.f / 128.f) + 1e-6f);
        const int t = ti * 4 + r;
        const unsigned short* zp = zb + (size_t)(row0 + t) * 2048 + h * 128 + tj * 8;
        ushort4 z0 = *(const ushort4*)(zp);
        ushort4 z1 = *(const ushort4*)(zp + 4);
        float zf[8] = {bf2f(z0.x), bf2f(z0.y), bf2f(z0.z), bf2f(z0.w),
                       bf2f(z1.x), bf2f(z1.y), bf2f(z1.z), bf2f(z1.w)};
        unsigned short* gp = gated_b + (size_t)(row0 + t) * 2048 + h * 128 + tj * 8;
#pragma unroll
        for (int j = 0; j < 8; ++j) {
            float g = o[r][j] * scale * norm_w[tj * 8 + j]
                    * (1.f / (1.f + expf(-zf[j])));
            gp[j] = f2bf(g);
        }
    }
}

extern "C" void kernel_launch(void* const* d_in, const int* in_sizes, int n_in,
                              void* d_out, int out_size, void* d_ws, size_t ws_size,
                              hipStream_t stream) {
    (void)in_sizes; (void)n_in; (void)out_size; (void)ws_size;
    const float* x          = (const float*)d_in[0];
    const int*   input_pos  = (const int*)d_in[1];
    const float* W_qkvz     = (const float*)d_in[2];
    const float* W_b        = (const float*)d_in[3];
    const float* W_a        = (const float*)d_in[4];
    const float* conv_w     = (const float*)d_in[5];
    const float* norm_w     = (const float*)d_in[6];
    const float* W_out      = (const float*)d_in[7];
    const float* conv_state = (const float*)d_in[8];
    const float* rec_state  = (const float*)d_in[9];
    float* out = (float*)d_out;
    float* ws  = (float*)d_ws;

    // workspace (float elems), peak 232.75 MiB with phase-based aliasing:
    float* qkv   = ws;                                 // 25,165,824 f (phase 2-3)
    float* Mbuf  = ws;                                 // 16,777,216 f (phase 4+, aliases qkv)
    unsigned short* gated_b = (unsigned short*)(ws + 16777216); // bf16 (phase 5+)
    float* qn    = ws + 25165824ull;                   // 8,388,608 f (phase 3+)
    float* kn    = qn + 8388608ull;
    float* vv    = kn + 8388608ull;
    unsigned short* xb  = (unsigned short*)qn;         // phase 1-2, aliases qn
    unsigned short* WqT = (unsigned short*)(qn + 4194304ull); // 8192x2048 bf16
    float* zbuf  = vv + 8388608ull;                    // region now holds z as bf16
    unsigned short* zb = (unsigned short*)zbuf;        // 8,388,608 bf16 (phase 2+)
    unsigned short* WoT = (unsigned short*)(zbuf + 8388608ull);
    float* alpha = zbuf + 8388608ull + 2097152ull;
    float* beta  = alpha + 65536ull;
    float* logc  = beta + 65536ull;

    // 0. weight transposes (merged) + alpha/beta (also emits xb = bf16(x))
    transpose_cast2<<<dim3(256, 64, 2), 256, 0, stream>>>(W_qkvz, WqT, W_out, WoT);
    ab_kernel<<<512, 256, 0, stream>>>(x, W_b, W_a, beta, alpha, xb);

    // 1. merged qkvz GEMM: cols<6144 -> qkv (f32), cols>=6144 -> zb (bf16)
    gemm256<<<dim3(8192 / 256, Mrows / 256), 512, 0, stream>>>(
        xb, WqT, qkv, zb, 2048, 2048, 2048);
    // 3. conv + silu + l2norm (last reader of qkv buffer)
    conv_kernel<<<dim3(Tt / 16, 12, Bb), 128, 0, stream>>>(
        qkv, conv_w, conv_state, input_pos, qn, kn, vv);
    // 4a. per-chunk prep: log-cumsum + M_c  (overwrites dead qkv region)
    chunk_prep<<<dim3(NCHUNK, Hh, Bb), 256, 0, stream>>>(
        kn, vv, alpha, beta, logc, Mbuf);
    // 4b. chunk-state recurrence, float4-parallel (Mbuf -> Sstates in place)
    state_scan<<<512, 256, 0, stream>>>(Mbuf, logc, rec_state, input_pos);
    // 4c. per-chunk outputs + RMSNorm + gate -> gated_b (bf16)
    chunk_out<<<dim3(NCHUNK, Hh, Bb), 256, 0, stream>>>(
        qn, kn, vv, beta, logc, Mbuf, norm_w, zb, gated_b);
    // 5. out = gated @ W_out   (MFMA bf16, 4-deep pipelined 128^2)
    gemm_bf16<<<dim3(2048 / 128, Mrows / 128), 256, 0, stream>>>(
        gated_b, WoT, out, 2048, 2048, 2048, 2048);
}